// Round 1
// baseline (2484.721 us; speedup 1.0000x reference)
//
#include <hip/hip_runtime.h>
#include <math.h>

constexpr int CIN  = 96;
constexpr int COUT = 192;
constexpr int TM   = 64;        // points per GEMM block
constexpr int CAPK = 1 << 20;   // key-space capacity (data needs 512000)

// ---------------- feat accumulator init (-inf) ----------------
__global__ void k_init_feat(float4* __restrict__ p, long long n4) {
  long long i = (long long)blockIdx.x * blockDim.x + threadIdx.x;
  long long s = (long long)gridDim.x * blockDim.x;
  float ni = __int_as_float(0xff800000);
  float4 v = make_float4(ni, ni, ni, ni);
  for (; i < n4; i += s) p[i] = v;
}

// ---------------- voxel extent (dims = max+1) ----------------
__global__ void k_vox(const float* __restrict__ xyz, int* __restrict__ dmax, int n) {
  int i = blockIdx.x * blockDim.x + threadIdx.x;
  int vx = 0, vy = 0, vz = 0;
  if (i < n) {
    vx = (int)floorf(xyz[3*i+0] * 0.5f);
    vy = (int)floorf(xyz[3*i+1] * 0.5f);
    vz = (int)floorf(xyz[3*i+2] * 0.5f);
  }
  for (int o = 32; o; o >>= 1) {
    vx = max(vx, __shfl_down(vx, o));
    vy = max(vy, __shfl_down(vy, o));
    vz = max(vz, __shfl_down(vz, o));
  }
  if ((threadIdx.x & 63) == 0) {
    atomicMax(&dmax[0], vx);
    atomicMax(&dmax[1], vy);
    atomicMax(&dmax[2], vz);
  }
}

// ---------------- keys + presence bitmap ----------------
__global__ void k_key(const float* __restrict__ xyz, const int* __restrict__ batch,
                      const int* __restrict__ dmax, int* __restrict__ keys,
                      int* __restrict__ pres, int n) {
  int i = blockIdx.x * blockDim.x + threadIdx.x;
  if (i >= n) return;
  int d0 = dmax[0] + 1, d1 = dmax[1] + 1, d2 = dmax[2] + 1;
  int vx = (int)floorf(xyz[3*i+0] * 0.5f);
  int vy = (int)floorf(xyz[3*i+1] * 0.5f);
  int vz = (int)floorf(xyz[3*i+2] * 0.5f);
  int key = ((batch[i] * d0 + vx) * d1 + vy) * d2 + vz;
  key = min(max(key, 0), CAPK - 1);
  keys[i] = key;
  pres[key] = 1;
}

// ---------------- prefix scan over presence (CAPK elems) ----------------
__global__ void k_scan1(const int4* __restrict__ pres4, int* __restrict__ bsums) {
  int t = threadIdx.x;
  int4 v = pres4[(size_t)blockIdx.x * 256 + t];
  int s = v.x + v.y + v.z + v.w;
  for (int o = 32; o; o >>= 1) s += __shfl_down(s, o);
  __shared__ int wsum[4];
  if ((t & 63) == 0) wsum[t >> 6] = s;
  __syncthreads();
  if (t == 0) bsums[blockIdx.x] = wsum[0] + wsum[1] + wsum[2] + wsum[3];
}

__global__ void k_scan2(const int* __restrict__ bsums, int* __restrict__ boffs,
                        int* __restrict__ num_u) {
  __shared__ int tmp[1024];
  int t = threadIdx.x;
  int v = bsums[t];
  tmp[t] = v;
  __syncthreads();
  for (int o = 1; o < 1024; o <<= 1) {
    int x = (t >= o) ? tmp[t - o] : 0;
    __syncthreads();
    tmp[t] += x;
    __syncthreads();
  }
  boffs[t] = tmp[t] - v;
  if (t == 1023) *num_u = tmp[t];
}

__global__ void k_scan3(int* __restrict__ pres, const int* __restrict__ boffs) {
  int t = threadIdx.x, b = blockIdx.x;
  int4 v = ((const int4*)pres)[(size_t)b * 256 + t];
  int s = v.x + v.y + v.z + v.w;
  __shared__ int tmp[256];
  tmp[t] = s;
  __syncthreads();
  for (int o = 1; o < 256; o <<= 1) {
    int x = (t >= o) ? tmp[t - o] : 0;
    __syncthreads();
    tmp[t] += x;
    __syncthreads();
  }
  int base = boffs[b] + tmp[t] - s;
  int4 r;
  r.x = base;
  r.y = base + v.x;
  r.z = r.y + v.y;
  r.w = r.z + v.z;
  ((int4*)pres)[(size_t)b * 256 + t] = r;
}

// ---------------- fused LayerNorm + Linear + segment-max scatter ----------------
__global__ __launch_bounds__(256) void k_fused(
    const float* __restrict__ feat, const float* __restrict__ W,
    const float* __restrict__ gamma, const float* __restrict__ beta,
    const int* __restrict__ keys, const int* __restrict__ rank,
    float* __restrict__ out_feat, int n) {
  __shared__ float Hs[TM * 100];   // stride 100 words -> conflict-free b128 frags
  __shared__ float g_lds[CIN], b_lds[CIN];
  __shared__ int segs[TM];
  int t = threadIdx.x;
  if (t < CIN) { g_lds[t] = gamma[t]; b_lds[t] = beta[t]; }

  // ---- LayerNorm: 4 threads per point (q = k-quarter) ----
  int p = t >> 2, q = t & 3;
  long long gpt = (long long)blockIdx.x * TM + p;
  float fv[24];
  float sum = 0.f, sq = 0.f;
  if (gpt < n) {
    const float* fr = feat + gpt * CIN + q * 24;
    #pragma unroll
    for (int j = 0; j < 24; j += 4) {
      float4 x = *(const float4*)(fr + j);
      fv[j] = x.x; fv[j+1] = x.y; fv[j+2] = x.z; fv[j+3] = x.w;
    }
    #pragma unroll
    for (int j = 0; j < 24; j++) { sum += fv[j]; sq += fv[j] * fv[j]; }
  } else {
    #pragma unroll
    for (int j = 0; j < 24; j++) fv[j] = 0.f;
  }
  sum += __shfl_xor(sum, 1); sq += __shfl_xor(sq, 1);
  sum += __shfl_xor(sum, 2); sq += __shfl_xor(sq, 2);
  float mu   = sum * (1.f / CIN);
  float var  = sq  * (1.f / CIN) - mu * mu;
  float rstd = rsqrtf(var + 1e-6f);
  __syncthreads();   // g_lds/b_lds ready
  #pragma unroll
  for (int j = 0; j < 24; j++) {
    int k = q * 24 + j;
    Hs[p * 100 + k] = (fv[j] - mu) * rstd * g_lds[k] + b_lds[k];
  }
  if (t < TM) {
    long long g = (long long)blockIdx.x * TM + t;
    segs[t] = (g < n) ? rank[keys[g]] : -1;
  }
  __syncthreads();

  // ---- GEMM: 64 pts x 192 outs, thread = 8 pts x 6 outs ----
  int pg = t & 7;       // point fragment: p = pg + 8r  (conflict-free LDS)
  int cg = t >> 3;      // c = cg*6 + j
  float acc[8][6];
  #pragma unroll
  for (int r = 0; r < 8; r++)
    #pragma unroll
    for (int j = 0; j < 6; j++) acc[r][j] = 0.f;

  #pragma unroll 2
  for (int k0 = 0; k0 < CIN; k0 += 4) {
    float4 wv[6];
    #pragma unroll
    for (int j = 0; j < 6; j++)
      wv[j] = *(const float4*)&W[(cg * 6 + j) * CIN + k0];
    #pragma unroll
    for (int r = 0; r < 8; r++) {
      float4 h4 = *(const float4*)&Hs[(pg + 8 * r) * 100 + k0];
      #pragma unroll
      for (int j = 0; j < 6; j++) {
        acc[r][j] = fmaf(h4.x, wv[j].x, acc[r][j]);
        acc[r][j] = fmaf(h4.y, wv[j].y, acc[r][j]);
        acc[r][j] = fmaf(h4.z, wv[j].z, acc[r][j]);
        acc[r][j] = fmaf(h4.w, wv[j].w, acc[r][j]);
      }
    }
  }

  // ---- segment max scatter (ordered-int float max trick) ----
  #pragma unroll
  for (int r = 0; r < 8; r++) {
    int seg = segs[pg + 8 * r];
    if (seg < 0) continue;
    float* orow = out_feat + (long long)seg * COUT + cg * 6;
    #pragma unroll
    for (int j = 0; j < 6; j++) {
      float v = acc[r][j];
      if (v >= 0.f) atomicMax((int*)(orow + j), __float_as_int(v));
      else atomicMin((unsigned int*)(orow + j), (unsigned int)__float_as_int(v));
    }
  }
}

// ---------------- scalar segment sums ----------------
__global__ void k_scatter(const float* __restrict__ xyz, const float* __restrict__ xyzc,
                          const int* __restrict__ batch, const int* __restrict__ keys,
                          const int* __restrict__ rank, float* __restrict__ out,
                          long long n) {
  long long i = (long long)blockIdx.x * blockDim.x + threadIdx.x;
  if (i >= n) return;
  int seg = rank[keys[i]];
  float c = xyzc[i];
  float* oxyz = out + n * 196;
  float* ocnt = out + n * 199;
  float* obat = out + n * 200;
  float* oval = out + n * 201;
  atomicAdd((int*)&oval[seg], 1);               // point count (exact int)
  atomicAdd(&ocnt[seg], c);                     // xyz_count sum
  atomicAdd(&oxyz[seg*3+0], xyz[i*3+0] * c);
  atomicAdd(&oxyz[seg*3+1], xyz[i*3+1] * c);
  atomicAdd(&oxyz[seg*3+2], xyz[i*3+2] * c);
  atomicAdd((int*)&obat[seg], batch[i]);        // batch sum (exact int)
}

// ---------------- finalize per segment ----------------
__global__ void k_fin(float* __restrict__ out, const int* __restrict__ num_u, long long n) {
  long long i = (long long)blockIdx.x * blockDim.x + threadIdx.x;
  if (i >= n) return;
  int nu = *num_u;
  float* ocrd = out + n * 192;
  float* oxyz = out + n * 196;
  float* ocnt = out + n * 199;
  float* obat = out + n * 200;
  float* oval = out + n * 201;
  if (i < nu) {
    int   cnt  = ((int*)oval)[i];
    int   bsum = ((int*)obat)[i];
    float cs   = fmaxf(ocnt[i], 1.0f);
    float x = oxyz[i*3+0] / cs, y = oxyz[i*3+1] / cs, z = oxyz[i*3+2] / cs;
    int bn = bsum / max(cnt, 1);
    oxyz[i*3+0] = x; oxyz[i*3+1] = y; oxyz[i*3+2] = z;
    ocnt[i] = cs;
    obat[i] = (float)bn;
    oval[i] = 1.0f;
    ocrd[i*4+0] = (float)bn;
    ocrd[i*4+1] = (float)(int)floorf(x * 0.5f);
    ocrd[i*4+2] = (float)(int)floorf(y * 0.5f);
    ocrd[i*4+3] = (float)(int)floorf(z * 0.5f);
  } else {
    oxyz[i*3+0] = 0.f; oxyz[i*3+1] = 0.f; oxyz[i*3+2] = 0.f;
    ocnt[i] = 1.0f;    // clip(0,1) per reference
    obat[i] = 0.f;
    oval[i] = 0.f;
    ocrd[i*4+0] = 0.f; ocrd[i*4+1] = 0.f; ocrd[i*4+2] = 0.f; ocrd[i*4+3] = 0.f;
  }
}

// ---------------- zero feat rows >= num_unique ----------------
__global__ void k_tail(float* __restrict__ out_feat, const int* __restrict__ num_u,
                       long long n) {
  long long nu = *num_u;
  long long start = nu * COUT, end = n * COUT;
  long long i = start + (long long)blockIdx.x * blockDim.x + threadIdx.x;
  long long s = (long long)gridDim.x * blockDim.x;
  for (; i < end; i += s) out_feat[i] = 0.f;
}

extern "C" void kernel_launch(void* const* d_in, const int* in_sizes, int n_in,
                              void* d_out, int out_size, void* d_ws, size_t ws_size,
                              hipStream_t stream) {
  const float* feat  = (const float*)d_in[0];
  const float* xyz   = (const float*)d_in[1];
  const float* xyzc  = (const float*)d_in[2];
  const int*   batch = (const int*)d_in[3];
  const float* W     = (const float*)d_in[4];
  const float* gamma = (const float*)d_in[5];
  const float* beta  = (const float*)d_in[6];
  long long n = in_sizes[3];
  float* out = (float*)d_out;

  // workspace layout
  char* wsb = (char*)d_ws;
  int* dmax  = (int*)wsb;                      // 4 ints (vox max x/y/z)
  int* num_u = dmax + 4;                       // 1 int
  int* keys  = (int*)(wsb + 32);               // n ints
  size_t pres_off = (32 + (size_t)n * 4 + 255) & ~(size_t)255;
  int* pres  = (int*)(wsb + pres_off);         // CAPK ints (presence -> ranks)
  int* bsums = (int*)(wsb + pres_off + (size_t)CAPK * 4);  // 1024
  int* boffs = bsums + 1024;                   // 1024

  hipMemsetAsync(dmax, 0, 32, stream);
  hipMemsetAsync(pres, 0, (size_t)CAPK * 4, stream);
  hipMemsetAsync(out + n * 196, 0, (size_t)n * 6 * sizeof(float), stream);

  int nb = (int)((n + 255) / 256);
  k_init_feat<<<2048, 256, 0, stream>>>((float4*)out, n * COUT / 4);
  k_vox<<<nb, 256, 0, stream>>>(xyz, dmax, (int)n);
  k_key<<<nb, 256, 0, stream>>>(xyz, batch, dmax, keys, pres, (int)n);
  k_scan1<<<CAPK / 1024, 256, 0, stream>>>((const int4*)pres, bsums);
  k_scan2<<<1, 1024, 0, stream>>>(bsums, boffs, num_u);
  k_scan3<<<CAPK / 1024, 256, 0, stream>>>(pres, boffs);
  k_fused<<<(int)((n + TM - 1) / TM), 256, 0, stream>>>(feat, W, gamma, beta,
                                                        keys, pres, out, (int)n);
  k_scatter<<<nb, 256, 0, stream>>>(xyz, xyzc, batch, keys, pres, out, n);
  k_fin<<<nb, 256, 0, stream>>>(out, num_u, n);
  k_tail<<<2048, 256, 0, stream>>>(out, num_u, n);
}

// Round 2
// 798.124 us; speedup vs baseline: 3.1132x; 3.1132x over previous
//
#include <hip/hip_runtime.h>
#include <math.h>

constexpr int CIN  = 96;
constexpr int COUT = 192;
constexpr int TM   = 64;        // points per GEMM block
constexpr int CAPK = 1 << 20;   // key-space capacity (data needs 512000)

// ---------------- voxel extent (dims = max+1) ----------------
__global__ void k_vox(const float* __restrict__ xyz, int* __restrict__ dmax, int n) {
  int i = blockIdx.x * blockDim.x + threadIdx.x;
  int vx = 0, vy = 0, vz = 0;
  if (i < n) {
    vx = (int)floorf(xyz[3*i+0] * 0.5f);
    vy = (int)floorf(xyz[3*i+1] * 0.5f);
    vz = (int)floorf(xyz[3*i+2] * 0.5f);
  }
  for (int o = 32; o; o >>= 1) {
    vx = max(vx, __shfl_down(vx, o));
    vy = max(vy, __shfl_down(vy, o));
    vz = max(vz, __shfl_down(vz, o));
  }
  if ((threadIdx.x & 63) == 0) {
    atomicMax(&dmax[0], vx);
    atomicMax(&dmax[1], vy);
    atomicMax(&dmax[2], vz);
  }
}

// ---------------- keys + presence bitmap ----------------
__global__ void k_key(const float* __restrict__ xyz, const int* __restrict__ batch,
                      const int* __restrict__ dmax, int* __restrict__ keys,
                      int* __restrict__ pres, int n) {
  int i = blockIdx.x * blockDim.x + threadIdx.x;
  if (i >= n) return;
  int d0 = dmax[0] + 1, d1 = dmax[1] + 1, d2 = dmax[2] + 1;
  int vx = (int)floorf(xyz[3*i+0] * 0.5f);
  int vy = (int)floorf(xyz[3*i+1] * 0.5f);
  int vz = (int)floorf(xyz[3*i+2] * 0.5f);
  int key = ((batch[i] * d0 + vx) * d1 + vy) * d2 + vz;
  key = min(max(key, 0), CAPK - 1);
  keys[i] = key;
  pres[key] = 1;
}

// ---------------- prefix scan over CAPK ints ----------------
__global__ void k_scan1(const int4* __restrict__ pres4, int* __restrict__ bsums) {
  int t = threadIdx.x;
  int4 v = pres4[(size_t)blockIdx.x * 256 + t];
  int s = v.x + v.y + v.z + v.w;
  for (int o = 32; o; o >>= 1) s += __shfl_down(s, o);
  __shared__ int wsum[4];
  if ((t & 63) == 0) wsum[t >> 6] = s;
  __syncthreads();
  if (t == 0) bsums[blockIdx.x] = wsum[0] + wsum[1] + wsum[2] + wsum[3];
}

__global__ void k_scan2(const int* __restrict__ bsums, int* __restrict__ boffs,
                        int* __restrict__ total_out) {
  __shared__ int tmp[1024];
  int t = threadIdx.x;
  int v = bsums[t];
  tmp[t] = v;
  __syncthreads();
  for (int o = 1; o < 1024; o <<= 1) {
    int x = (t >= o) ? tmp[t - o] : 0;
    __syncthreads();
    tmp[t] += x;
    __syncthreads();
  }
  boffs[t] = tmp[t] - v;
  if (t == 1023) *total_out = tmp[t];
}

__global__ void k_scan3(int* __restrict__ pres, const int* __restrict__ boffs) {
  int t = threadIdx.x, b = blockIdx.x;
  int4 v = ((const int4*)pres)[(size_t)b * 256 + t];
  int s = v.x + v.y + v.z + v.w;
  __shared__ int tmp[256];
  tmp[t] = s;
  __syncthreads();
  for (int o = 1; o < 256; o <<= 1) {
    int x = (t >= o) ? tmp[t - o] : 0;
    __syncthreads();
    tmp[t] += x;
    __syncthreads();
  }
  int base = boffs[b] + tmp[t] - s;
  int4 r;
  r.x = base;
  r.y = base + v.x;
  r.z = r.y + v.y;
  r.w = r.z + v.z;
  ((int4*)pres)[(size_t)b * 256 + t] = r;
}

// =====================================================================
// FAST PATH (CSR gather, needs ~325MB workspace)
// =====================================================================

// segment id per point, per-segment counts, scalar segment sums
__global__ void k_count(const float* __restrict__ xyz, const float* __restrict__ xyzc,
                        const int* __restrict__ batch, const int* __restrict__ keys,
                        const int* __restrict__ rank, int* __restrict__ segs,
                        int* __restrict__ cnts, float* __restrict__ out, long long n) {
  long long i = (long long)blockIdx.x * blockDim.x + threadIdx.x;
  if (i >= n) return;
  int seg = rank[keys[i]];
  segs[i] = seg;
  atomicAdd(&cnts[seg], 1);
  float c = xyzc[i];
  float* oxyz = out + n * 196;
  float* ocnt = out + n * 199;
  float* obat = out + n * 200;
  atomicAdd(&ocnt[seg], c);
  atomicAdd(&oxyz[seg*3+0], xyz[i*3+0] * c);
  atomicAdd(&oxyz[seg*3+1], xyz[i*3+1] * c);
  atomicAdd(&oxyz[seg*3+2], xyz[i*3+2] * c);
  atomicAdd((int*)&obat[seg], batch[i]);        // batch sum (exact int)
}

// scatter point indices into CSR lists
__global__ void k_plist(const int* __restrict__ segs, const int* __restrict__ cscan,
                        int* __restrict__ cursor, int* __restrict__ plist, long long n) {
  long long i = (long long)blockIdx.x * blockDim.x + threadIdx.x;
  if (i >= n) return;
  int seg = segs[i];
  int pos = cscan[seg] + atomicAdd(&cursor[seg], 1);
  plist[pos] = (int)i;
}

// LayerNorm + Linear -> H (workspace), no atomics
__global__ __launch_bounds__(256) void k_H(
    const float* __restrict__ feat, const float* __restrict__ W,
    const float* __restrict__ gamma, const float* __restrict__ beta,
    float* __restrict__ H, long long n) {
  __shared__ float Hs[TM * 100];   // stride 100 words -> conflict-free b128 frags
  __shared__ float g_lds[CIN], b_lds[CIN];
  int t = threadIdx.x;
  if (t < CIN) { g_lds[t] = gamma[t]; b_lds[t] = beta[t]; }

  // ---- LayerNorm: 4 threads per point (q = k-quarter) ----
  int p = t >> 2, q = t & 3;
  long long gpt = (long long)blockIdx.x * TM + p;
  float fv[24];
  float sum = 0.f, sq = 0.f;
  if (gpt < n) {
    const float* fr = feat + gpt * CIN + q * 24;
    #pragma unroll
    for (int j = 0; j < 24; j += 4) {
      float4 x = *(const float4*)(fr + j);
      fv[j] = x.x; fv[j+1] = x.y; fv[j+2] = x.z; fv[j+3] = x.w;
    }
    #pragma unroll
    for (int j = 0; j < 24; j++) { sum += fv[j]; sq += fv[j] * fv[j]; }
  } else {
    #pragma unroll
    for (int j = 0; j < 24; j++) fv[j] = 0.f;
  }
  sum += __shfl_xor(sum, 1); sq += __shfl_xor(sq, 1);
  sum += __shfl_xor(sum, 2); sq += __shfl_xor(sq, 2);
  float mu   = sum * (1.f / CIN);
  float var  = sq  * (1.f / CIN) - mu * mu;
  float rstd = rsqrtf(var + 1e-6f);
  __syncthreads();   // g_lds/b_lds ready
  #pragma unroll
  for (int j = 0; j < 24; j++) {
    int k = q * 24 + j;
    Hs[p * 100 + k] = (fv[j] - mu) * rstd * g_lds[k] + b_lds[k];
  }
  __syncthreads();

  // ---- GEMM: 64 pts x 192 outs, thread = 8 pts x 6 outs ----
  int pg = t & 7;       // point fragment: p = pg + 8r  (conflict-free LDS)
  int cg = t >> 3;      // c = cg*6 + j
  float acc[8][6];
  #pragma unroll
  for (int r = 0; r < 8; r++)
    #pragma unroll
    for (int j = 0; j < 6; j++) acc[r][j] = 0.f;

  #pragma unroll 2
  for (int k0 = 0; k0 < CIN; k0 += 4) {
    float4 wv[6];
    #pragma unroll
    for (int j = 0; j < 6; j++)
      wv[j] = *(const float4*)&W[(cg * 6 + j) * CIN + k0];
    #pragma unroll
    for (int r = 0; r < 8; r++) {
      float4 h4 = *(const float4*)&Hs[(pg + 8 * r) * 100 + k0];
      #pragma unroll
      for (int j = 0; j < 6; j++) {
        acc[r][j] = fmaf(h4.x, wv[j].x, acc[r][j]);
        acc[r][j] = fmaf(h4.y, wv[j].y, acc[r][j]);
        acc[r][j] = fmaf(h4.z, wv[j].z, acc[r][j]);
        acc[r][j] = fmaf(h4.w, wv[j].w, acc[r][j]);
      }
    }
  }

  #pragma unroll
  for (int r = 0; r < 8; r++) {
    long long gp = (long long)blockIdx.x * TM + pg + 8 * r;
    if (gp >= n) continue;
    float* hrow = H + gp * COUT + cg * 6;
    *(float2*)(hrow + 0) = make_float2(acc[r][0], acc[r][1]);
    *(float2*)(hrow + 2) = make_float2(acc[r][2], acc[r][3]);
    *(float2*)(hrow + 4) = make_float2(acc[r][4], acc[r][5]);
  }
}

// per-segment max gather; also zero-fills rows >= num_unique
__global__ __launch_bounds__(256) void k_gather(
    const float* __restrict__ H, const int* __restrict__ plist,
    const int* __restrict__ cscan, const int* __restrict__ num_u,
    float* __restrict__ out_feat, long long n) {
  int t = threadIdx.x;
  long long s = (long long)blockIdx.x * 4 + (t >> 6);
  if (s >= n) return;
  int lane = t & 63;
  float* orow = out_feat + s * COUT;
  int nu = *num_u;
  if (s >= nu) {
    orow[lane] = 0.f; orow[lane + 64] = 0.f; orow[lane + 128] = 0.f;
    return;
  }
  int st = cscan[s], en = cscan[s + 1];
  float ni = __int_as_float(0xff800000);
  float m0 = ni, m1 = ni, m2 = ni;
  for (int p = st; p < en; ++p) {
    const float* h = H + (long long)plist[p] * COUT;
    m0 = fmaxf(m0, h[lane]);
    m1 = fmaxf(m1, h[lane + 64]);
    m2 = fmaxf(m2, h[lane + 128]);
  }
  orow[lane] = m0; orow[lane + 64] = m1; orow[lane + 128] = m2;
}

// finalize per segment (fast path: count from CSR scan diff)
__global__ void k_fin2(float* __restrict__ out, const int* __restrict__ num_u,
                       const int* __restrict__ cscan, long long n) {
  long long i = (long long)blockIdx.x * blockDim.x + threadIdx.x;
  if (i >= n) return;
  int nu = *num_u;
  float* ocrd = out + n * 192;
  float* oxyz = out + n * 196;
  float* ocnt = out + n * 199;
  float* obat = out + n * 200;
  float* oval = out + n * 201;
  if (i < nu) {
    int   cnt  = cscan[i + 1] - cscan[i];
    int   bsum = ((int*)obat)[i];
    float cs   = fmaxf(ocnt[i], 1.0f);
    float x = oxyz[i*3+0] / cs, y = oxyz[i*3+1] / cs, z = oxyz[i*3+2] / cs;
    int bn = bsum / max(cnt, 1);
    oxyz[i*3+0] = x; oxyz[i*3+1] = y; oxyz[i*3+2] = z;
    ocnt[i] = cs;
    obat[i] = (float)bn;
    oval[i] = 1.0f;
    ocrd[i*4+0] = (float)bn;
    ocrd[i*4+1] = (float)(int)floorf(x * 0.5f);
    ocrd[i*4+2] = (float)(int)floorf(y * 0.5f);
    ocrd[i*4+3] = (float)(int)floorf(z * 0.5f);
  } else {
    oxyz[i*3+0] = 0.f; oxyz[i*3+1] = 0.f; oxyz[i*3+2] = 0.f;
    ocnt[i] = 1.0f;
    obat[i] = 0.f;
    oval[i] = 0.f;
    ocrd[i*4+0] = 0.f; ocrd[i*4+1] = 0.f; ocrd[i*4+2] = 0.f; ocrd[i*4+3] = 0.f;
  }
}

// =====================================================================
// FALLBACK PATH (round-1 atomic scatter) — used if ws_size too small
// =====================================================================
__global__ void k_init_feat(float4* __restrict__ p, long long n4) {
  long long i = (long long)blockIdx.x * blockDim.x + threadIdx.x;
  long long s = (long long)gridDim.x * blockDim.x;
  float ni = __int_as_float(0xff800000);
  float4 v = make_float4(ni, ni, ni, ni);
  for (; i < n4; i += s) p[i] = v;
}

__global__ __launch_bounds__(256) void k_fused(
    const float* __restrict__ feat, const float* __restrict__ W,
    const float* __restrict__ gamma, const float* __restrict__ beta,
    const int* __restrict__ keys, const int* __restrict__ rank,
    float* __restrict__ out_feat, int n) {
  __shared__ float Hs[TM * 100];
  __shared__ float g_lds[CIN], b_lds[CIN];
  __shared__ int segs[TM];
  int t = threadIdx.x;
  if (t < CIN) { g_lds[t] = gamma[t]; b_lds[t] = beta[t]; }
  int p = t >> 2, q = t & 3;
  long long gpt = (long long)blockIdx.x * TM + p;
  float fv[24];
  float sum = 0.f, sq = 0.f;
  if (gpt < n) {
    const float* fr = feat + gpt * CIN + q * 24;
    #pragma unroll
    for (int j = 0; j < 24; j += 4) {
      float4 x = *(const float4*)(fr + j);
      fv[j] = x.x; fv[j+1] = x.y; fv[j+2] = x.z; fv[j+3] = x.w;
    }
    #pragma unroll
    for (int j = 0; j < 24; j++) { sum += fv[j]; sq += fv[j] * fv[j]; }
  } else {
    #pragma unroll
    for (int j = 0; j < 24; j++) fv[j] = 0.f;
  }
  sum += __shfl_xor(sum, 1); sq += __shfl_xor(sq, 1);
  sum += __shfl_xor(sum, 2); sq += __shfl_xor(sq, 2);
  float mu   = sum * (1.f / CIN);
  float var  = sq  * (1.f / CIN) - mu * mu;
  float rstd = rsqrtf(var + 1e-6f);
  __syncthreads();
  #pragma unroll
  for (int j = 0; j < 24; j++) {
    int k = q * 24 + j;
    Hs[p * 100 + k] = (fv[j] - mu) * rstd * g_lds[k] + b_lds[k];
  }
  if (t < TM) {
    long long g = (long long)blockIdx.x * TM + t;
    segs[t] = (g < n) ? rank[keys[g]] : -1;
  }
  __syncthreads();
  int pg = t & 7, cg = t >> 3;
  float acc[8][6];
  #pragma unroll
  for (int r = 0; r < 8; r++)
    #pragma unroll
    for (int j = 0; j < 6; j++) acc[r][j] = 0.f;
  #pragma unroll 2
  for (int k0 = 0; k0 < CIN; k0 += 4) {
    float4 wv[6];
    #pragma unroll
    for (int j = 0; j < 6; j++)
      wv[j] = *(const float4*)&W[(cg * 6 + j) * CIN + k0];
    #pragma unroll
    for (int r = 0; r < 8; r++) {
      float4 h4 = *(const float4*)&Hs[(pg + 8 * r) * 100 + k0];
      #pragma unroll
      for (int j = 0; j < 6; j++) {
        acc[r][j] = fmaf(h4.x, wv[j].x, acc[r][j]);
        acc[r][j] = fmaf(h4.y, wv[j].y, acc[r][j]);
        acc[r][j] = fmaf(h4.z, wv[j].z, acc[r][j]);
        acc[r][j] = fmaf(h4.w, wv[j].w, acc[r][j]);
      }
    }
  }
  #pragma unroll
  for (int r = 0; r < 8; r++) {
    int seg = segs[pg + 8 * r];
    if (seg < 0) continue;
    float* orow = out_feat + (long long)seg * COUT + cg * 6;
    #pragma unroll
    for (int j = 0; j < 6; j++) {
      float v = acc[r][j];
      if (v >= 0.f) atomicMax((int*)(orow + j), __float_as_int(v));
      else atomicMin((unsigned int*)(orow + j), (unsigned int)__float_as_int(v));
    }
  }
}

__global__ void k_scatter(const float* __restrict__ xyz, const float* __restrict__ xyzc,
                          const int* __restrict__ batch, const int* __restrict__ keys,
                          const int* __restrict__ rank, float* __restrict__ out,
                          long long n) {
  long long i = (long long)blockIdx.x * blockDim.x + threadIdx.x;
  if (i >= n) return;
  int seg = rank[keys[i]];
  float c = xyzc[i];
  float* oxyz = out + n * 196;
  float* ocnt = out + n * 199;
  float* obat = out + n * 200;
  float* oval = out + n * 201;
  atomicAdd((int*)&oval[seg], 1);
  atomicAdd(&ocnt[seg], c);
  atomicAdd(&oxyz[seg*3+0], xyz[i*3+0] * c);
  atomicAdd(&oxyz[seg*3+1], xyz[i*3+1] * c);
  atomicAdd(&oxyz[seg*3+2], xyz[i*3+2] * c);
  atomicAdd((int*)&obat[seg], batch[i]);
}

__global__ void k_fin(float* __restrict__ out, const int* __restrict__ num_u, long long n) {
  long long i = (long long)blockIdx.x * blockDim.x + threadIdx.x;
  if (i >= n) return;
  int nu = *num_u;
  float* ocrd = out + n * 192;
  float* oxyz = out + n * 196;
  float* ocnt = out + n * 199;
  float* obat = out + n * 200;
  float* oval = out + n * 201;
  if (i < nu) {
    int   cnt  = ((int*)oval)[i];
    int   bsum = ((int*)obat)[i];
    float cs   = fmaxf(ocnt[i], 1.0f);
    float x = oxyz[i*3+0] / cs, y = oxyz[i*3+1] / cs, z = oxyz[i*3+2] / cs;
    int bn = bsum / max(cnt, 1);
    oxyz[i*3+0] = x; oxyz[i*3+1] = y; oxyz[i*3+2] = z;
    ocnt[i] = cs;
    obat[i] = (float)bn;
    oval[i] = 1.0f;
    ocrd[i*4+0] = (float)bn;
    ocrd[i*4+1] = (float)(int)floorf(x * 0.5f);
    ocrd[i*4+2] = (float)(int)floorf(y * 0.5f);
    ocrd[i*4+3] = (float)(int)floorf(z * 0.5f);
  } else {
    oxyz[i*3+0] = 0.f; oxyz[i*3+1] = 0.f; oxyz[i*3+2] = 0.f;
    ocnt[i] = 1.0f;
    obat[i] = 0.f;
    oval[i] = 0.f;
    ocrd[i*4+0] = 0.f; ocrd[i*4+1] = 0.f; ocrd[i*4+2] = 0.f; ocrd[i*4+3] = 0.f;
  }
}

__global__ void k_tail(float* __restrict__ out_feat, const int* __restrict__ num_u,
                       long long n) {
  long long nu = *num_u;
  long long start = nu * COUT, end = n * COUT;
  long long i = start + (long long)blockIdx.x * blockDim.x + threadIdx.x;
  long long s = (long long)gridDim.x * blockDim.x;
  for (; i < end; i += s) out_feat[i] = 0.f;
}

extern "C" void kernel_launch(void* const* d_in, const int* in_sizes, int n_in,
                              void* d_out, int out_size, void* d_ws, size_t ws_size,
                              hipStream_t stream) {
  const float* feat  = (const float*)d_in[0];
  const float* xyz   = (const float*)d_in[1];
  const float* xyzc  = (const float*)d_in[2];
  const int*   batch = (const int*)d_in[3];
  const float* W     = (const float*)d_in[4];
  const float* gamma = (const float*)d_in[5];
  const float* beta  = (const float*)d_in[6];
  long long n = in_sizes[3];
  float* out = (float*)d_out;
  int nb = (int)((n + 255) / 256);

  // ---- workspace layout (fast path) ----
  char* wsb = (char*)d_ws;
  size_t off = 0;
  int* dmax   = (int*)wsb;             off += 64;          // [0..2]=vox max, [3]=dummy total
  int* num_u  = dmax + 4;
  int* keys   = (int*)(wsb + off);     off += (size_t)n * 4;
  int* segs   = (int*)(wsb + off);     off += (size_t)n * 4;
  int* plist  = (int*)(wsb + off);     off += (size_t)n * 4;
  off = (off + 255) & ~(size_t)255;
  int* pres   = (int*)(wsb + off);     off += (size_t)CAPK * 4;  // presence -> rank
  int* cnts   = (int*)(wsb + off);     off += (size_t)CAPK * 4;  // counts -> csr starts
  int* cursor = (int*)(wsb + off);     off += (size_t)CAPK * 4;
  int* bsums  = (int*)(wsb + off);     off += 4096;
  int* boffs  = (int*)(wsb + off);     off += 4096;
  off = (off + 255) & ~(size_t)255;
  float* H    = (float*)(wsb + off);   off += (size_t)n * COUT * 4;
  bool fast = (ws_size >= off);

  hipMemsetAsync(dmax, 0, 64, stream);
  hipMemsetAsync(out + n * 196, 0, (size_t)n * 6 * sizeof(float), stream);

  if (fast) {
    hipMemsetAsync(pres, 0, (size_t)CAPK * 12, stream);   // pres+cnts+cursor
    k_vox   <<<nb, 256, 0, stream>>>(xyz, dmax, (int)n);
    k_key   <<<nb, 256, 0, stream>>>(xyz, batch, dmax, keys, pres, (int)n);
    k_scan1 <<<CAPK / 1024, 256, 0, stream>>>((const int4*)pres, bsums);
    k_scan2 <<<1, 1024, 0, stream>>>(bsums, boffs, num_u);
    k_scan3 <<<CAPK / 1024, 256, 0, stream>>>(pres, boffs);
    k_count <<<nb, 256, 0, stream>>>(xyz, xyzc, batch, keys, pres, segs, cnts, out, n);
    k_scan1 <<<CAPK / 1024, 256, 0, stream>>>((const int4*)cnts, bsums);
    k_scan2 <<<1, 1024, 0, stream>>>(bsums, boffs, &dmax[3]);
    k_scan3 <<<CAPK / 1024, 256, 0, stream>>>(cnts, boffs);
    k_plist <<<nb, 256, 0, stream>>>(segs, cnts, cursor, plist, n);
    k_H     <<<(int)((n + TM - 1) / TM), 256, 0, stream>>>(feat, W, gamma, beta, H, n);
    k_gather<<<(int)((n + 3) / 4), 256, 0, stream>>>(H, plist, cnts, num_u, out, n);
    k_fin2  <<<nb, 256, 0, stream>>>(out, num_u, cnts, n);
  } else {
    // round-1 atomic path (small workspace)
    size_t pres_off = (64 + (size_t)n * 4 + 255) & ~(size_t)255;
    int* presf  = (int*)(wsb + pres_off);
    int* bsumsf = (int*)(wsb + pres_off + (size_t)CAPK * 4);
    int* boffsf = bsumsf + 1024;
    hipMemsetAsync(presf, 0, (size_t)CAPK * 4, stream);
    k_init_feat<<<2048, 256, 0, stream>>>((float4*)out, n * COUT / 4);
    k_vox   <<<nb, 256, 0, stream>>>(xyz, dmax, (int)n);
    k_key   <<<nb, 256, 0, stream>>>(xyz, batch, dmax, keys, presf, (int)n);
    k_scan1 <<<CAPK / 1024, 256, 0, stream>>>((const int4*)presf, bsumsf);
    k_scan2 <<<1, 1024, 0, stream>>>(bsumsf, boffsf, num_u);
    k_scan3 <<<CAPK / 1024, 256, 0, stream>>>(presf, boffsf);
    k_fused <<<(int)((n + TM - 1) / TM), 256, 0, stream>>>(feat, W, gamma, beta,
                                                           keys, presf, out, (int)n);
    k_scatter<<<nb, 256, 0, stream>>>(xyz, xyzc, batch, keys, presf, out, n);
    k_fin   <<<nb, 256, 0, stream>>>(out, num_u, n);
    k_tail  <<<2048, 256, 0, stream>>>(out, num_u, n);
  }
}

// Round 3
// 454.321 us; speedup vs baseline: 5.4691x; 1.7567x over previous
//
#include <hip/hip_runtime.h>
#include <math.h>

constexpr int CIN   = 96;
constexpr int COUT  = 192;
constexpr int CAPK2 = 1 << 21;   // fixed key space: batch(3b) vx(6b) vy(6b) vz(6b)
constexpr int NSC   = 1 << 19;   // cnts scan span (>= n+1)
constexpr int LDW   = 104;       // LDS row stride (bf16 units): 208B, 16B-mult, 2-way-free
constexpr int LDO   = 208;       // output staging row stride (bf16 units): 416B

typedef short v8s  __attribute__((ext_vector_type(8)));
typedef float f32x4 __attribute__((ext_vector_type(4)));

__device__ __forceinline__ unsigned short f2bf(float f) {
  unsigned u = __float_as_uint(f);
  u += 0x7fff + ((u >> 16) & 1);          // RNE
  return (unsigned short)(u >> 16);
}
__device__ __forceinline__ float bf2f(unsigned short s) {
  return __uint_as_float((unsigned)s << 16);
}

// ---------------- keys + presence (fixed lexicographic packing) ----------------
__global__ void k_key(const float* __restrict__ xyz, const int* __restrict__ batch,
                      int* __restrict__ keys, int* __restrict__ pres, int n) {
  int i = blockIdx.x * blockDim.x + threadIdx.x;
  if (i >= n) return;
  int vx = (int)floorf(xyz[3*i+0] * 0.5f);
  int vy = (int)floorf(xyz[3*i+1] * 0.5f);
  int vz = (int)floorf(xyz[3*i+2] * 0.5f);
  int key = (batch[i] << 18) | (vx << 12) | (vy << 6) | vz;
  keys[i] = key;
  pres[key] = 1;
}

// ---------------- prefix scan (1024 elems/block) ----------------
__global__ void k_scan1(const int4* __restrict__ a4, int* __restrict__ bsums) {
  int t = threadIdx.x;
  int4 v = a4[(size_t)blockIdx.x * 256 + t];
  int s = v.x + v.y + v.z + v.w;
  for (int o = 32; o; o >>= 1) s += __shfl_down(s, o);
  __shared__ int wsum[4];
  if ((t & 63) == 0) wsum[t >> 6] = s;
  __syncthreads();
  if (t == 0) bsums[blockIdx.x] = wsum[0] + wsum[1] + wsum[2] + wsum[3];
}

__global__ void k_scan2(const int* __restrict__ bsums, int* __restrict__ boffs,
                        int* __restrict__ total_out, int nb) {
  __shared__ int tmp[1024];
  int t = threadIdx.x;
  int i0 = 2 * t, i1 = 2 * t + 1;
  int v0 = (i0 < nb) ? bsums[i0] : 0;
  int v1 = (i1 < nb) ? bsums[i1] : 0;
  int s = v0 + v1;
  tmp[t] = s;
  __syncthreads();
  for (int o = 1; o < 1024; o <<= 1) {
    int x = (t >= o) ? tmp[t - o] : 0;
    __syncthreads();
    tmp[t] += x;
    __syncthreads();
  }
  int base = tmp[t] - s;
  if (i0 < nb) boffs[i0] = base;
  if (i1 < nb) boffs[i1] = base + v0;
  if (t == 1023) *total_out = tmp[1023];
}

__global__ void k_scan3(int* __restrict__ a, const int* __restrict__ boffs) {
  int t = threadIdx.x, b = blockIdx.x;
  int4 v = ((const int4*)a)[(size_t)b * 256 + t];
  int s = v.x + v.y + v.z + v.w;
  __shared__ int tmp[256];
  tmp[t] = s;
  __syncthreads();
  for (int o = 1; o < 256; o <<= 1) {
    int x = (t >= o) ? tmp[t - o] : 0;
    __syncthreads();
    tmp[t] += x;
    __syncthreads();
  }
  int base = boffs[b] + tmp[t] - s;
  int4 r;
  r.x = base;
  r.y = base + v.x;
  r.z = r.y + v.y;
  r.w = r.z + v.z;
  ((int4*)a)[(size_t)b * 256 + t] = r;
}

// ---------------- per-point seg id, counts, scalar segment sums ----------------
__global__ void k_count(const float* __restrict__ xyz, const float* __restrict__ xyzc,
                        const int* __restrict__ batch, const int* __restrict__ keys,
                        const int* __restrict__ rank, int* __restrict__ segs,
                        int* __restrict__ cnts, float* __restrict__ out, long long n) {
  long long i = (long long)blockIdx.x * blockDim.x + threadIdx.x;
  if (i >= n) return;
  int seg = rank[keys[i]];
  segs[i] = seg;
  atomicAdd(&cnts[seg], 1);
  float c = xyzc[i];
  float* oxyz = out + n * 196;
  float* ocnt = out + n * 199;
  float* obat = out + n * 200;
  atomicAdd(&ocnt[seg], c);
  atomicAdd(&oxyz[seg*3+0], xyz[i*3+0] * c);
  atomicAdd(&oxyz[seg*3+1], xyz[i*3+1] * c);
  atomicAdd(&oxyz[seg*3+2], xyz[i*3+2] * c);
  atomicAdd((int*)&obat[seg], batch[i]);        // batch sum (exact int)
}

// ---------------- CSR point lists ----------------
__global__ void k_plist(const int* __restrict__ segs, const int* __restrict__ cscan,
                        int* __restrict__ cursor, int* __restrict__ plist, long long n) {
  long long i = (long long)blockIdx.x * blockDim.x + threadIdx.x;
  if (i >= n) return;
  int seg = segs[i];
  int pos = cscan[seg] + atomicAdd(&cursor[seg], 1);
  plist[pos] = (int)i;
}

// ---------------- LayerNorm + MFMA Linear -> H (bf16) ----------------
__global__ __launch_bounds__(256) void k_H(
    const float* __restrict__ feat, const float* __restrict__ W,
    const float* __restrict__ gamma, const float* __restrict__ beta,
    unsigned short* __restrict__ H, long long n) {
  __shared__ unsigned short Wl[COUT * LDW];   // 39936 B; reused as [64][LDO] out-stage
  __shared__ unsigned short Hl[64 * LDW];     // 13312 B
  __shared__ float g_lds[CIN], b_lds[CIN];
  int t = threadIdx.x;
  if (t < CIN) { g_lds[t] = gamma[t]; b_lds[t] = beta[t]; }

  // ---- stage W (fp32 -> bf16) ----
  #pragma unroll
  for (int i = 0; i < 18; i++) {
    int f4 = t + 256 * i;                    // float4 index, 4608 total
    float4 w = ((const float4*)W)[f4];
    int flat = f4 * 4;
    int row = flat / CIN, col = flat % CIN;  // no row straddle (96 % 4 == 0)
    uint2 pk;
    pk.x = (unsigned)f2bf(w.x) | ((unsigned)f2bf(w.y) << 16);
    pk.y = (unsigned)f2bf(w.z) | ((unsigned)f2bf(w.w) << 16);
    *(uint2*)&Wl[row * LDW + col] = pk;
  }

  // ---- LayerNorm: 4 threads per point ----
  int p = t >> 2, q = t & 3;
  long long gp = (long long)blockIdx.x * 64 + p;
  float fv[24];
  float sum = 0.f, sq = 0.f;
  if (gp < n) {
    const float* fr = feat + gp * CIN + q * 24;
    #pragma unroll
    for (int j = 0; j < 24; j += 4) {
      float4 x = *(const float4*)(fr + j);
      fv[j] = x.x; fv[j+1] = x.y; fv[j+2] = x.z; fv[j+3] = x.w;
    }
    #pragma unroll
    for (int j = 0; j < 24; j++) { sum += fv[j]; sq += fv[j] * fv[j]; }
  } else {
    #pragma unroll
    for (int j = 0; j < 24; j++) fv[j] = 0.f;
  }
  sum += __shfl_xor(sum, 1); sq += __shfl_xor(sq, 1);
  sum += __shfl_xor(sum, 2); sq += __shfl_xor(sq, 2);
  float mu   = sum * (1.f / CIN);
  float var  = sq  * (1.f / CIN) - mu * mu;
  float rstd = rsqrtf(var + 1e-6f);
  __syncthreads();                            // g_lds/b_lds visible
  unsigned pk[12];
  #pragma unroll
  for (int j = 0; j < 12; j++) {
    int k = q * 24 + 2 * j;
    float v0 = (fv[2*j]   - mu) * rstd * g_lds[k]   + b_lds[k];
    float v1 = (fv[2*j+1] - mu) * rstd * g_lds[k+1] + b_lds[k+1];
    pk[j] = (unsigned)f2bf(v0) | ((unsigned)f2bf(v1) << 16);
  }
  {
    uint4* dst = (uint4*)&Hl[p * LDW + q * 24];
    dst[0] = make_uint4(pk[0], pk[1], pk[2],  pk[3]);
    dst[1] = make_uint4(pk[4], pk[5], pk[6],  pk[7]);
    dst[2] = make_uint4(pk[8], pk[9], pk[10], pk[11]);
  }
  __syncthreads();                            // Hl + Wl ready

  // ---- MFMA: 4 waves x 16 rows; N=192 (12 tiles), K=96 (3 steps) ----
  int wv = t >> 6, lane = t & 63, r = lane & 15, g = lane >> 4;
  f32x4 acc[12];
  #pragma unroll
  for (int i = 0; i < 12; i++) acc[i] = (f32x4){0.f, 0.f, 0.f, 0.f};
  int arow = (wv * 16 + r) * LDW;
  #pragma unroll
  for (int ks = 0; ks < 3; ks++) {
    v8s a = *(const v8s*)&Hl[arow + ks * 32 + g * 8];
    #pragma unroll
    for (int t16 = 0; t16 < 12; t16++) {
      v8s b = *(const v8s*)&Wl[(t16 * 16 + r) * LDW + ks * 32 + g * 8];
      acc[t16] = __builtin_amdgcn_mfma_f32_16x16x32_bf16(a, b, acc[t16], 0, 0, 0);
    }
  }
  __syncthreads();                            // Wl reads done -> reuse as out-stage

  unsigned short* Ol = Wl;                    // [64][LDO]
  #pragma unroll
  for (int t16 = 0; t16 < 12; t16++) {
    #pragma unroll
    for (int rr = 0; rr < 4; rr++) {
      Ol[(wv * 16 + g * 4 + rr) * LDO + t16 * 16 + r] = f2bf(acc[t16][rr]);
    }
  }
  __syncthreads();

  // ---- coalesced bf16 store: 4 threads per row, 96B each ----
  int row = t >> 2, c4 = t & 3;
  long long gp2 = (long long)blockIdx.x * 64 + row;
  if (gp2 < n) {
    const uint4* src = (const uint4*)&Ol[row * LDO + c4 * 48];
    uint4* dst = (uint4*)&H[gp2 * COUT + c4 * 48];
    #pragma unroll
    for (int i = 0; i < 6; i++) dst[i] = src[i];
  }
}

// ---------------- per-segment max gather + finalize ----------------
__global__ __launch_bounds__(256) void k_gather(
    const unsigned short* __restrict__ H, const int* __restrict__ plist,
    const int* __restrict__ cscan, const int* __restrict__ num_u,
    float* __restrict__ out, long long n) {
  int t = threadIdx.x;
  long long s = (long long)blockIdx.x * 4 + (t >> 6);
  if (s >= n) return;
  int lane = t & 63;
  float* orow = out + s * COUT;
  float* ocrd = out + n * 192;
  float* oxyz = out + n * 196;
  float* ocnt = out + n * 199;
  float* obat = out + n * 200;
  float* oval = out + n * 201;
  int nu = *num_u;
  if (s >= nu) {
    orow[lane] = 0.f; orow[lane + 64] = 0.f; orow[lane + 128] = 0.f;
    if (lane == 0) {
      oxyz[s*3+0] = 0.f; oxyz[s*3+1] = 0.f; oxyz[s*3+2] = 0.f;
      ocnt[s] = 1.0f;  obat[s] = 0.f;  oval[s] = 0.f;
      ocrd[s*4+0] = 0.f; ocrd[s*4+1] = 0.f; ocrd[s*4+2] = 0.f; ocrd[s*4+3] = 0.f;
    }
    return;
  }
  int st = cscan[s], en = cscan[s + 1];
  int cnt = en - st;
  float ni = __int_as_float(0xff800000);
  float m0 = ni, m1 = ni, m2 = ni;
  for (int base = 0; base < cnt; base += 64) {
    int lim = min(64, cnt - base);
    int pl = plist[st + base + min(lane, lim - 1)];
    for (int j = 0; j < lim; j += 4) {
      int i1 = min(j + 1, lim - 1), i2 = min(j + 2, lim - 1), i3 = min(j + 3, lim - 1);
      long long r0 = __shfl(pl, j),  r1 = __shfl(pl, i1);
      long long r2 = __shfl(pl, i2), r3 = __shfl(pl, i3);
      const unsigned short* h0 = H + r0 * COUT;
      const unsigned short* h1 = H + r1 * COUT;
      const unsigned short* h2 = H + r2 * COUT;
      const unsigned short* h3 = H + r3 * COUT;
      unsigned short a0 = h0[lane], a1 = h0[lane+64], a2 = h0[lane+128];
      unsigned short b0 = h1[lane], b1 = h1[lane+64], b2 = h1[lane+128];
      unsigned short c0 = h2[lane], c1 = h2[lane+64], c2 = h2[lane+128];
      unsigned short d0 = h3[lane], d1 = h3[lane+64], d2 = h3[lane+128];
      m0 = fmaxf(fmaxf(fmaxf(m0, bf2f(a0)), bf2f(b0)), fmaxf(bf2f(c0), bf2f(d0)));
      m1 = fmaxf(fmaxf(fmaxf(m1, bf2f(a1)), bf2f(b1)), fmaxf(bf2f(c1), bf2f(d1)));
      m2 = fmaxf(fmaxf(fmaxf(m2, bf2f(a2)), bf2f(b2)), fmaxf(bf2f(c2), bf2f(d2)));
    }
  }
  orow[lane] = m0; orow[lane + 64] = m1; orow[lane + 128] = m2;

  if (lane == 0) {   // finalize segment s
    int   bsum = ((int*)obat)[s];
    float cs   = fmaxf(ocnt[s], 1.0f);
    float x = oxyz[s*3+0] / cs, y = oxyz[s*3+1] / cs, z = oxyz[s*3+2] / cs;
    int bn = bsum / max(cnt, 1);
    oxyz[s*3+0] = x; oxyz[s*3+1] = y; oxyz[s*3+2] = z;
    ocnt[s] = cs;
    obat[s] = (float)bn;
    oval[s] = 1.0f;
    ocrd[s*4+0] = (float)bn;
    ocrd[s*4+1] = (float)(int)floorf(x * 0.5f);
    ocrd[s*4+2] = (float)(int)floorf(y * 0.5f);
    ocrd[s*4+3] = (float)(int)floorf(z * 0.5f);
  }
}

extern "C" void kernel_launch(void* const* d_in, const int* in_sizes, int n_in,
                              void* d_out, int out_size, void* d_ws, size_t ws_size,
                              hipStream_t stream) {
  const float* feat  = (const float*)d_in[0];
  const float* xyz   = (const float*)d_in[1];
  const float* xyzc  = (const float*)d_in[2];
  const int*   batch = (const int*)d_in[3];
  const float* W     = (const float*)d_in[4];
  const float* gamma = (const float*)d_in[5];
  const float* beta  = (const float*)d_in[6];
  long long n = in_sizes[3];
  float* out = (float*)d_out;
  int nb = (int)((n + 255) / 256);

  // ---- workspace layout ----
  char* wsb = (char*)d_ws;
  size_t off = 0;
  int* hdr    = (int*)wsb;             off += 64;   // hdr[0]=num_u, hdr[1]=scratch total
  int* num_u  = hdr;
  int* keys   = (int*)(wsb + off);     off += (size_t)n * 4;
  int* segs   = (int*)(wsb + off);     off += (size_t)n * 4;
  int* plist  = (int*)(wsb + off);     off += (size_t)n * 4;
  off = (off + 255) & ~(size_t)255;
  char* zbase = wsb + off;                          // zeroed span start
  int* cursor = (int*)(wsb + off);     off += (size_t)n * 4;
  int* pres   = (int*)(wsb + off);     off += (size_t)CAPK2 * 4;
  int* cnts   = (int*)(wsb + off);     off += (size_t)NSC * 4;
  size_t zlen = (size_t)(wsb + off - zbase);
  int* bsums  = (int*)(wsb + off);     off += 2048 * 4;
  int* boffs  = (int*)(wsb + off);     off += 2048 * 4;
  off = (off + 255) & ~(size_t)255;
  unsigned short* H = (unsigned short*)(wsb + off);

  hipMemsetAsync(zbase, 0, zlen, stream);                                  // cursor+pres+cnts
  hipMemsetAsync(out + n * 196, 0, (size_t)n * 6 * sizeof(float), stream); // sum regions

  k_key   <<<nb, 256, 0, stream>>>(xyz, batch, keys, pres, (int)n);
  k_scan1 <<<CAPK2 / 1024, 256, 0, stream>>>((const int4*)pres, bsums);
  k_scan2 <<<1, 1024, 0, stream>>>(bsums, boffs, num_u, CAPK2 / 1024);
  k_scan3 <<<CAPK2 / 1024, 256, 0, stream>>>(pres, boffs);
  k_count <<<nb, 256, 0, stream>>>(xyz, xyzc, batch, keys, pres, segs, cnts, out, n);
  k_scan1 <<<NSC / 1024, 256, 0, stream>>>((const int4*)cnts, bsums);
  k_scan2 <<<1, 1024, 0, stream>>>(bsums, boffs, &hdr[1], NSC / 1024);
  k_scan3 <<<NSC / 1024, 256, 0, stream>>>(cnts, boffs);
  k_plist <<<nb, 256, 0, stream>>>(segs, cnts, cursor, plist, n);
  k_H     <<<(int)((n + 63) / 64), 256, 0, stream>>>(feat, W, gamma, beta, H, n);
  k_gather<<<(int)((n + 3) / 4), 256, 0, stream>>>(H, plist, cnts, num_u, out, n);
}

// Round 4
// 342.186 us; speedup vs baseline: 7.2613x; 1.3277x over previous
//
#include <hip/hip_runtime.h>
#include <math.h>

constexpr int CIN   = 96;
constexpr int COUT  = 192;
constexpr int NSC   = 1 << 19;   // scan span >= 8*40*40*40 = 512000 keys
constexpr int LDW   = 104;       // Hl/Wl row stride (shorts)
constexpr int REC_S = 224;       // record size in shorts (448 B, 64B-line aligned)
constexpr int REC_B = 448;

typedef short v8s  __attribute__((ext_vector_type(8)));
typedef float f32x4 __attribute__((ext_vector_type(4)));

__device__ __forceinline__ unsigned short f2bf(float f) {
  unsigned u = __float_as_uint(f);
  u += 0x7fff + ((u >> 16) & 1);          // RNE
  return (unsigned short)(u >> 16);
}
__device__ __forceinline__ float bf2f(unsigned short s) {
  return __uint_as_float((unsigned)s << 16);
}
__device__ __forceinline__ unsigned long long packic(int c) {
  // hi32 = presence indicator, lo32 = count
  return ((unsigned long long)(c > 0) << 32) | (unsigned)c;
}

// ---------------- keys + per-point slot + per-key counts ----------------
__global__ void k_key(const float* __restrict__ xyz, const int* __restrict__ batch,
                      int* __restrict__ keys, int* __restrict__ slot,
                      int* __restrict__ cntk, int n) {
  int i = blockIdx.x * blockDim.x + threadIdx.x;
  if (i >= n) return;
  int vx = min(max((int)floorf(xyz[3*i+0] * 0.5f), 0), 39);
  int vy = min(max((int)floorf(xyz[3*i+1] * 0.5f), 0), 39);
  int vz = min(max((int)floorf(xyz[3*i+2] * 0.5f), 0), 39);
  int key = ((batch[i] * 40 + vx) * 40 + vy) * 40 + vz;   // lexicographic, < 512000
  keys[i] = key;
  slot[i] = atomicAdd(&cntk[key], 1);
}

// ---------------- dual prefix scan (rank over presence, pos over counts) ----------------
__global__ void k_scan1(const int4* __restrict__ cnt4,
                        unsigned long long* __restrict__ bsums) {
  int t = threadIdx.x;
  int4 v = cnt4[(size_t)blockIdx.x * 256 + t];
  unsigned long long s = packic(v.x) + packic(v.y) + packic(v.z) + packic(v.w);
  for (int o = 32; o; o >>= 1) s += __shfl_down(s, o);
  __shared__ unsigned long long wsum[4];
  if ((t & 63) == 0) wsum[t >> 6] = s;
  __syncthreads();
  if (t == 0) bsums[blockIdx.x] = wsum[0] + wsum[1] + wsum[2] + wsum[3];
}

__global__ void k_scan2(const unsigned long long* __restrict__ bsums,
                        unsigned long long* __restrict__ boffs,
                        int* __restrict__ hdr) {
  __shared__ unsigned long long tmp[256];
  int t = threadIdx.x;                      // 256 threads, 512 sums
  unsigned long long v0 = bsums[2*t], v1 = bsums[2*t+1];
  unsigned long long s = v0 + v1;
  tmp[t] = s;
  __syncthreads();
  for (int o = 1; o < 256; o <<= 1) {
    unsigned long long x = (t >= o) ? tmp[t - o] : 0ULL;
    __syncthreads();
    tmp[t] += x;
    __syncthreads();
  }
  unsigned long long base = tmp[t] - s;
  boffs[2*t] = base;
  boffs[2*t+1] = base + v0;
  if (t == 255) hdr[0] = (int)(tmp[255] >> 32);   // num_unique
}

__global__ void k_scan3(const int4* __restrict__ cnt4,
                        const unsigned long long* __restrict__ boffs,
                        int* __restrict__ rankK, int* __restrict__ posK) {
  int t = threadIdx.x, b = blockIdx.x;
  int4 v = cnt4[(size_t)b * 256 + t];
  unsigned long long q0 = packic(v.x), q1 = packic(v.y), q2 = packic(v.z), q3 = packic(v.w);
  unsigned long long s = q0 + q1 + q2 + q3;
  __shared__ unsigned long long tmp[256];
  tmp[t] = s;
  __syncthreads();
  for (int o = 1; o < 256; o <<= 1) {
    unsigned long long x = (t >= o) ? tmp[t - o] : 0ULL;
    __syncthreads();
    tmp[t] += x;
    __syncthreads();
  }
  unsigned long long e0 = boffs[b] + tmp[t] - s;
  unsigned long long e1 = e0 + q0, e2 = e1 + q1, e3 = e2 + q2;
  int4 rk = make_int4((int)(e0 >> 32), (int)(e1 >> 32), (int)(e2 >> 32), (int)(e3 >> 32));
  int4 ps = make_int4((int)(unsigned)e0, (int)(unsigned)e1, (int)(unsigned)e2, (int)(unsigned)e3);
  ((int4*)rankK)[(size_t)b * 256 + t] = rk;
  ((int4*)posK)[(size_t)b * 256 + t] = ps;
}

// ---------------- LayerNorm + MFMA Linear -> permuted 448B records ----------------
__global__ __launch_bounds__(256) void k_H(
    const float* __restrict__ feat, const float* __restrict__ xyz,
    const float* __restrict__ xyzc, const int* __restrict__ batch,
    const float* __restrict__ W, const float* __restrict__ gamma,
    const float* __restrict__ beta, const int* __restrict__ keys,
    const int* __restrict__ slot, const int* __restrict__ cntk,
    const int* __restrict__ rankK, const int* __restrict__ posK,
    char* __restrict__ rec, long long n) {
  __shared__ unsigned short Wl[COUT * LDW];   // 39936B; reused as Ol[64][REC_S]
  __shared__ unsigned short Hl[64 * LDW];     // 13312B
  __shared__ float g_lds[CIN], b_lds[CIN];
  __shared__ int spos[64];
  int t = threadIdx.x;
  if (t < CIN) { g_lds[t] = gamma[t]; b_lds[t] = beta[t]; }

  // ---- stage W (fp32 -> bf16) ----
  #pragma unroll
  for (int i = 0; i < 18; i++) {
    int f4 = t + 256 * i;                    // 4608 float4 total
    float4 w = ((const float4*)W)[f4];
    int flat = f4 * 4;
    int row = flat / CIN, col = flat % CIN;
    uint2 pk2;
    pk2.x = (unsigned)f2bf(w.x) | ((unsigned)f2bf(w.y) << 16);
    pk2.y = (unsigned)f2bf(w.z) | ((unsigned)f2bf(w.w) << 16);
    *(uint2*)&Wl[row * LDW + col] = pk2;
  }

  // ---- LayerNorm: 4 threads per point ----
  int p = t >> 2, q = t & 3;
  long long gp = (long long)blockIdx.x * 64 + p;
  float sx = 0.f, sy = 0.f, sz = 0.f, sc = 0.f;
  int sb = 0, srk = 0, sbase = 0, scn = 0, sps = 0;
  if (q == 0 && gp < n) {                    // per-point scalar payload
    int key = keys[gp];
    int pk_ = posK[key];
    sps = pk_ + slot[gp];
    srk = rankK[key];
    sbase = pk_;
    scn = cntk[key];
    sx = xyz[gp*3+0]; sy = xyz[gp*3+1]; sz = xyz[gp*3+2];
    sc = xyzc[gp]; sb = batch[gp];
  }
  float fv[24];
  float sum = 0.f, sq = 0.f;
  if (gp < n) {
    const float* fr = feat + gp * CIN + q * 24;
    #pragma unroll
    for (int j = 0; j < 24; j += 4) {
      float4 x = *(const float4*)(fr + j);
      fv[j] = x.x; fv[j+1] = x.y; fv[j+2] = x.z; fv[j+3] = x.w;
    }
    #pragma unroll
    for (int j = 0; j < 24; j++) { sum += fv[j]; sq += fv[j] * fv[j]; }
  } else {
    #pragma unroll
    for (int j = 0; j < 24; j++) fv[j] = 0.f;
  }
  sum += __shfl_xor(sum, 1); sq += __shfl_xor(sq, 1);
  sum += __shfl_xor(sum, 2); sq += __shfl_xor(sq, 2);
  float mu   = sum * (1.f / CIN);
  float var  = sq  * (1.f / CIN) - mu * mu;
  float rstd = rsqrtf(var + 1e-6f);
  __syncthreads();                            // g_lds/b_lds + Wl visible
  unsigned pk[12];
  #pragma unroll
  for (int j = 0; j < 12; j++) {
    int k = q * 24 + 2 * j;
    float v0 = (fv[2*j]   - mu) * rstd * g_lds[k]   + b_lds[k];
    float v1 = (fv[2*j+1] - mu) * rstd * g_lds[k+1] + b_lds[k+1];
    pk[j] = (unsigned)f2bf(v0) | ((unsigned)f2bf(v1) << 16);
  }
  {
    uint4* dst = (uint4*)&Hl[p * LDW + q * 24];
    dst[0] = make_uint4(pk[0], pk[1], pk[2],  pk[3]);
    dst[1] = make_uint4(pk[4], pk[5], pk[6],  pk[7]);
    dst[2] = make_uint4(pk[8], pk[9], pk[10], pk[11]);
  }
  __syncthreads();                            // Hl + Wl ready

  // ---- MFMA: 4 waves x 16 rows; N=192 (12 tiles), K=96 (3 steps) ----
  int wv = t >> 6, lane = t & 63, r = lane & 15, g = lane >> 4;
  f32x4 acc[12];
  #pragma unroll
  for (int i = 0; i < 12; i++) acc[i] = (f32x4){0.f, 0.f, 0.f, 0.f};
  int arow = (wv * 16 + r) * LDW;
  #pragma unroll
  for (int ks = 0; ks < 3; ks++) {
    v8s a = *(const v8s*)&Hl[arow + ks * 32 + g * 8];
    #pragma unroll
    for (int t16 = 0; t16 < 12; t16++) {
      v8s b = *(const v8s*)&Wl[(t16 * 16 + r) * LDW + ks * 32 + g * 8];
      acc[t16] = __builtin_amdgcn_mfma_f32_16x16x32_bf16(a, b, acc[t16], 0, 0, 0);
    }
  }
  __syncthreads();                            // Wl reads done -> reuse as record stage

  unsigned short* Ol = Wl;                    // [64][REC_S]
  #pragma unroll
  for (int t16 = 0; t16 < 12; t16++) {
    #pragma unroll
    for (int rr = 0; rr < 4; rr++) {
      Ol[(wv * 16 + g * 4 + rr) * REC_S + t16 * 16 + r] = f2bf(acc[t16][rr]);
    }
  }
  if (q == 0) {                               // scalar payload into record tail
    float* tl = (float*)&Ol[p * REC_S + 192];
    tl[0] = sx; tl[1] = sy; tl[2] = sz; tl[3] = sc;
    ((int*)tl)[4] = sb; ((int*)tl)[5] = srk; ((int*)tl)[6] = sbase; ((int*)tl)[7] = scn;
    spos[p] = sps;
  }
  __syncthreads();

  // ---- coalesced record store: 4 threads per point, 112B each ----
  int row = t >> 2, c4 = t & 3;
  long long gp2 = (long long)blockIdx.x * 64 + row;
  if (gp2 < n) {
    const uint4* src = (const uint4*)&Ol[row * REC_S + c4 * 56];
    uint4* dst = (uint4*)(rec + (size_t)spos[row] * REC_B + c4 * 112);
    #pragma unroll
    for (int i = 0; i < 7; i++) dst[i] = src[i];
  }
}

// ---------------- segment max + scalar finalize (window-ownership, no atomics) ----------------
__global__ __launch_bounds__(256) void k_gather(
    const char* __restrict__ rec, float* __restrict__ out, long long n) {
  __shared__ int s_start[256], s_cnt[256], s_rank[256];
  __shared__ int hscan[256];
  int t = threadIdx.x;
  int p0 = blockIdx.x * 64;
  const int* t0 = (const int*)(rec + (size_t)p0 * REC_B + 384);
  int base0 = t0[6], cnt0 = t0[7];
  int range_start = (base0 == p0) ? p0 : base0 + cnt0;
  int p1 = p0 + 64, range_end;
  if (p1 >= (int)n) {
    range_end = (int)n;
  } else {
    const int* t1 = (const int*)(rec + (size_t)p1 * REC_B + 384);
    int base1 = t1[6], cnt1 = t1[7];
    range_end = (base1 == p1) ? p1 : base1 + cnt1;
  }
  int RL = range_end - range_start;           // <= 64 + max_seg  (<< 256)
  int hd = 0, cn_ = 0, rk_ = 0;
  int pp = range_start + t;
  if (t < RL) {
    const int* tf = (const int*)(rec + (size_t)pp * REC_B + 384);
    hd = (tf[6] == pp);
    if (hd) { cn_ = tf[7]; rk_ = tf[5]; }
  }
  hscan[t] = hd;
  __syncthreads();
  for (int o = 1; o < 256; o <<= 1) {
    int x = (t >= o) ? hscan[t - o] : 0;
    __syncthreads();
    hscan[t] += x;
    __syncthreads();
  }
  int ns = hscan[255];
  if (hd) {
    int idx = hscan[t] - 1;
    s_start[idx] = pp; s_cnt[idx] = cn_; s_rank[idx] = rk_;
  }
  __syncthreads();

  int wv = t >> 6, lane = t & 63;
  float* ocrd = out + n * 192;
  float* oxyz = out + n * 196;
  float* ocnt = out + n * 199;
  float* obat = out + n * 200;
  float* oval = out + n * 201;
  for (int j = wv; j < ns; j += 4) {
    int st = s_start[j], cn = s_cnt[j], rk = s_rank[j];
    float ni = __int_as_float(0xff800000);
    float m0 = ni, m1 = ni, m2 = ni;
    for (int qq = 0; qq < cn; qq++) {
      const unsigned short* h = (const unsigned short*)(rec + (size_t)(st + qq) * REC_B);
      m0 = fmaxf(m0, bf2f(h[lane]));
      m1 = fmaxf(m1, bf2f(h[lane + 64]));
      m2 = fmaxf(m2, bf2f(h[lane + 128]));
    }
    float ax = 0.f, ay = 0.f, az = 0.f, ac = 0.f; int ab = 0;
    for (int qq = lane; qq < cn; qq += 64) {
      const float* tf = (const float*)(rec + (size_t)(st + qq) * REC_B + 384);
      float c = tf[3];
      ax += tf[0] * c; ay += tf[1] * c; az += tf[2] * c; ac += c;
      ab += ((const int*)tf)[4];
    }
    for (int o = 32; o; o >>= 1) {
      ax += __shfl_down(ax, o); ay += __shfl_down(ay, o);
      az += __shfl_down(az, o); ac += __shfl_down(ac, o);
      ab += __shfl_down(ab, o);
    }
    float* orow = out + (size_t)rk * COUT;
    orow[lane] = m0; orow[lane + 64] = m1; orow[lane + 128] = m2;
    if (lane == 0) {
      float cs = fmaxf(ac, 1.0f);
      float x = ax / cs, y = ay / cs, z = az / cs;
      int bn = ab / max(cn, 1);
      oxyz[rk*3+0] = x; oxyz[rk*3+1] = y; oxyz[rk*3+2] = z;
      ocnt[rk] = cs;
      obat[rk] = (float)bn;
      oval[rk] = 1.0f;
      ocrd[rk*4+0] = (float)bn;
      ocrd[rk*4+1] = (float)(int)floorf(x * 0.5f);
      ocrd[rk*4+2] = (float)(int)floorf(y * 0.5f);
      ocrd[rk*4+3] = (float)(int)floorf(z * 0.5f);
    }
  }
}

// ---------------- tail rows >= num_unique: zeros + defaults ----------------
__global__ void k_tail(float* __restrict__ out, const int* __restrict__ hdr, long long n) {
  int nu = hdr[0];
  long long s = (long long)blockIdx.x * 4 + (threadIdx.x >> 6);
  if (s < nu || s >= n) return;
  int lane = threadIdx.x & 63;
  float* orow = out + s * COUT;
  orow[lane] = 0.f; orow[lane + 64] = 0.f; orow[lane + 128] = 0.f;
  if (lane == 0) {
    float* ocrd = out + n * 192;
    float* oxyz = out + n * 196;
    float* ocnt = out + n * 199;
    float* obat = out + n * 200;
    float* oval = out + n * 201;
    oxyz[s*3+0] = 0.f; oxyz[s*3+1] = 0.f; oxyz[s*3+2] = 0.f;
    ocnt[s] = 1.0f;
    obat[s] = 0.f;
    oval[s] = 0.f;
    ocrd[s*4+0] = 0.f; ocrd[s*4+1] = 0.f; ocrd[s*4+2] = 0.f; ocrd[s*4+3] = 0.f;
  }
}

extern "C" void kernel_launch(void* const* d_in, const int* in_sizes, int n_in,
                              void* d_out, int out_size, void* d_ws, size_t ws_size,
                              hipStream_t stream) {
  const float* feat  = (const float*)d_in[0];
  const float* xyz   = (const float*)d_in[1];
  const float* xyzc  = (const float*)d_in[2];
  const int*   batch = (const int*)d_in[3];
  const float* W     = (const float*)d_in[4];
  const float* gamma = (const float*)d_in[5];
  const float* beta  = (const float*)d_in[6];
  long long n = in_sizes[3];
  float* out = (float*)d_out;

  // ---- workspace layout (~190 MB) ----
  char* wsb = (char*)d_ws;
  size_t off = 0;
  int* hdr   = (int*)wsb;              off += 256;                // hdr[0] = num_unique
  int* keys  = (int*)(wsb + off);      off += (size_t)n * 4;
  int* slot  = (int*)(wsb + off);      off += (size_t)n * 4;
  off = (off + 255) & ~(size_t)255;
  int* cntk  = (int*)(wsb + off);      off += (size_t)NSC * 4;    // memset 0
  int* rankK = (int*)(wsb + off);      off += (size_t)NSC * 4;
  int* posK  = (int*)(wsb + off);      off += (size_t)NSC * 4;
  unsigned long long* bsums = (unsigned long long*)(wsb + off); off += 512 * 8;
  unsigned long long* boffs = (unsigned long long*)(wsb + off); off += 512 * 8;
  off = (off + 255) & ~(size_t)255;
  char* rec  = wsb + off;              off += (size_t)n * REC_B;

  hipMemsetAsync(cntk, 0, (size_t)NSC * 4, stream);

  int nb  = (int)((n + 255) / 256);
  int nb64 = (int)((n + 63) / 64);
  k_key   <<<nb, 256, 0, stream>>>(xyz, batch, keys, slot, cntk, (int)n);
  k_scan1 <<<NSC / 1024, 256, 0, stream>>>((const int4*)cntk, bsums);
  k_scan2 <<<1, 256, 0, stream>>>(bsums, boffs, hdr);
  k_scan3 <<<NSC / 1024, 256, 0, stream>>>((const int4*)cntk, boffs, rankK, posK);
  k_H     <<<nb64, 256, 0, stream>>>(feat, xyz, xyzc, batch, W, gamma, beta,
                                     keys, slot, cntk, rankK, posK, rec, n);
  k_gather<<<nb64, 256, 0, stream>>>(rec, out, n);
  k_tail  <<<(int)((n + 3) / 4), 256, 0, stream>>>(out, hdr, n);
}

// Round 5
// 341.736 us; speedup vs baseline: 7.2709x; 1.0013x over previous
//
#include <hip/hip_runtime.h>
#include <math.h>

constexpr int CIN   = 96;
constexpr int COUT  = 192;
constexpr int NSC   = 1 << 19;   // scan span >= 8*40*40*40 = 512000 keys
constexpr int LDW   = 104;       // Hl/Wl row stride (shorts)
constexpr int REC_S = 224;       // record size in shorts (448 B, 64B-line aligned)
constexpr int REC_B = 448;

typedef short v8s  __attribute__((ext_vector_type(8)));
typedef float f32x4 __attribute__((ext_vector_type(4)));

__device__ __forceinline__ unsigned short f2bf(float f) {
  unsigned u = __float_as_uint(f);
  u += 0x7fff + ((u >> 16) & 1);          // RNE
  return (unsigned short)(u >> 16);
}
__device__ __forceinline__ float bf2f(unsigned short s) {
  return __uint_as_float((unsigned)s << 16);
}
__device__ __forceinline__ unsigned long long packic(int c) {
  // hi32 = presence indicator, lo32 = count
  return ((unsigned long long)(c > 0) << 32) | (unsigned)c;
}

// ---------------- fast zero (runtime fillBuffer for 2MB is 185us!) ----------------
__global__ void k_zero(int4* __restrict__ p, int n4) {
  int i = blockIdx.x * blockDim.x + threadIdx.x;
  int s = gridDim.x * blockDim.x;
  int4 z = make_int4(0, 0, 0, 0);
  for (; i < n4; i += s) p[i] = z;
}

// ---------------- keys + per-point slot + per-key counts ----------------
__global__ void k_key(const float* __restrict__ xyz, const int* __restrict__ batch,
                      int* __restrict__ keys, int* __restrict__ slot,
                      int* __restrict__ cntk, int n) {
  int i = blockIdx.x * blockDim.x + threadIdx.x;
  if (i >= n) return;
  int vx = min(max((int)floorf(xyz[3*i+0] * 0.5f), 0), 39);
  int vy = min(max((int)floorf(xyz[3*i+1] * 0.5f), 0), 39);
  int vz = min(max((int)floorf(xyz[3*i+2] * 0.5f), 0), 39);
  int key = ((batch[i] * 40 + vx) * 40 + vy) * 40 + vz;   // lexicographic, < 512000
  keys[i] = key;
  slot[i] = atomicAdd(&cntk[key], 1);
}

// ---------------- dual prefix scan (rank over presence, pos over counts) ----------------
__global__ void k_scan1(const int4* __restrict__ cnt4,
                        unsigned long long* __restrict__ bsums) {
  int t = threadIdx.x;
  int4 v = cnt4[(size_t)blockIdx.x * 256 + t];
  unsigned long long s = packic(v.x) + packic(v.y) + packic(v.z) + packic(v.w);
  for (int o = 32; o; o >>= 1) s += __shfl_down(s, o);
  __shared__ unsigned long long wsum[4];
  if ((t & 63) == 0) wsum[t >> 6] = s;
  __syncthreads();
  if (t == 0) bsums[blockIdx.x] = wsum[0] + wsum[1] + wsum[2] + wsum[3];
}

__global__ void k_scan2(const unsigned long long* __restrict__ bsums,
                        unsigned long long* __restrict__ boffs,
                        int* __restrict__ hdr) {
  __shared__ unsigned long long tmp[256];
  int t = threadIdx.x;                      // 256 threads, 512 sums
  unsigned long long v0 = bsums[2*t], v1 = bsums[2*t+1];
  unsigned long long s = v0 + v1;
  tmp[t] = s;
  __syncthreads();
  for (int o = 1; o < 256; o <<= 1) {
    unsigned long long x = (t >= o) ? tmp[t - o] : 0ULL;
    __syncthreads();
    tmp[t] += x;
    __syncthreads();
  }
  unsigned long long base = tmp[t] - s;
  boffs[2*t] = base;
  boffs[2*t+1] = base + v0;
  if (t == 255) hdr[0] = (int)(tmp[255] >> 32);   // num_unique
}

__global__ void k_scan3(const int4* __restrict__ cnt4,
                        const unsigned long long* __restrict__ boffs,
                        int* __restrict__ rankK, int* __restrict__ posK) {
  int t = threadIdx.x, b = blockIdx.x;
  int4 v = cnt4[(size_t)b * 256 + t];
  unsigned long long q0 = packic(v.x), q1 = packic(v.y), q2 = packic(v.z), q3 = packic(v.w);
  unsigned long long s = q0 + q1 + q2 + q3;
  __shared__ unsigned long long tmp[256];
  tmp[t] = s;
  __syncthreads();
  for (int o = 1; o < 256; o <<= 1) {
    unsigned long long x = (t >= o) ? tmp[t - o] : 0ULL;
    __syncthreads();
    tmp[t] += x;
    __syncthreads();
  }
  unsigned long long e0 = boffs[b] + tmp[t] - s;
  unsigned long long e1 = e0 + q0, e2 = e1 + q1, e3 = e2 + q2;
  int4 rk = make_int4((int)(e0 >> 32), (int)(e1 >> 32), (int)(e2 >> 32), (int)(e3 >> 32));
  int4 ps = make_int4((int)(unsigned)e0, (int)(unsigned)e1, (int)(unsigned)e2, (int)(unsigned)e3);
  ((int4*)rankK)[(size_t)b * 256 + t] = rk;
  ((int4*)posK)[(size_t)b * 256 + t] = ps;
}

// ---------------- LayerNorm + MFMA Linear -> permuted 448B records ----------------
__global__ __launch_bounds__(256) void k_H(
    const float* __restrict__ feat, const float* __restrict__ xyz,
    const float* __restrict__ xyzc, const int* __restrict__ batch,
    const float* __restrict__ W, const float* __restrict__ gamma,
    const float* __restrict__ beta, const int* __restrict__ keys,
    const int* __restrict__ slot, const int* __restrict__ cntk,
    const int* __restrict__ rankK, const int* __restrict__ posK,
    char* __restrict__ rec, long long n) {
  __shared__ unsigned short Wl[COUT * LDW];   // 39936B; reused as Ol[64][REC_S]
  __shared__ unsigned short Hl[64 * LDW];     // 13312B
  __shared__ float g_lds[CIN], b_lds[CIN];
  __shared__ int spos[64];
  int t = threadIdx.x;
  if (t < CIN) { g_lds[t] = gamma[t]; b_lds[t] = beta[t]; }

  // ---- stage W (fp32 -> bf16) ----
  #pragma unroll
  for (int i = 0; i < 18; i++) {
    int f4 = t + 256 * i;                    // 4608 float4 total
    float4 w = ((const float4*)W)[f4];
    int flat = f4 * 4;
    int row = flat / CIN, col = flat % CIN;
    uint2 pk2;
    pk2.x = (unsigned)f2bf(w.x) | ((unsigned)f2bf(w.y) << 16);
    pk2.y = (unsigned)f2bf(w.z) | ((unsigned)f2bf(w.w) << 16);
    *(uint2*)&Wl[row * LDW + col] = pk2;
  }

  // ---- LayerNorm: 4 threads per point ----
  int p = t >> 2, q = t & 3;
  long long gp = (long long)blockIdx.x * 64 + p;
  float sx = 0.f, sy = 0.f, sz = 0.f, sc = 0.f;
  int sb = 0, srk = 0, sbase = 0, scn = 0, sps = 0;
  if (q == 0 && gp < n) {                    // per-point scalar payload
    int key = keys[gp];
    int pk_ = posK[key];
    sps = pk_ + slot[gp];
    srk = rankK[key];
    sbase = pk_;
    scn = cntk[key];
    sx = xyz[gp*3+0]; sy = xyz[gp*3+1]; sz = xyz[gp*3+2];
    sc = xyzc[gp]; sb = batch[gp];
  }
  float fv[24];
  float sum = 0.f, sq = 0.f;
  if (gp < n) {
    const float* fr = feat + gp * CIN + q * 24;
    #pragma unroll
    for (int j = 0; j < 24; j += 4) {
      float4 x = *(const float4*)(fr + j);
      fv[j] = x.x; fv[j+1] = x.y; fv[j+2] = x.z; fv[j+3] = x.w;
    }
    #pragma unroll
    for (int j = 0; j < 24; j++) { sum += fv[j]; sq += fv[j] * fv[j]; }
  } else {
    #pragma unroll
    for (int j = 0; j < 24; j++) fv[j] = 0.f;
  }
  sum += __shfl_xor(sum, 1); sq += __shfl_xor(sq, 1);
  sum += __shfl_xor(sum, 2); sq += __shfl_xor(sq, 2);
  float mu   = sum * (1.f / CIN);
  float var  = sq  * (1.f / CIN) - mu * mu;
  float rstd = rsqrtf(var + 1e-6f);
  __syncthreads();                            // g_lds/b_lds + Wl visible
  unsigned pk[12];
  #pragma unroll
  for (int j = 0; j < 12; j++) {
    int k = q * 24 + 2 * j;
    float v0 = (fv[2*j]   - mu) * rstd * g_lds[k]   + b_lds[k];
    float v1 = (fv[2*j+1] - mu) * rstd * g_lds[k+1] + b_lds[k+1];
    pk[j] = (unsigned)f2bf(v0) | ((unsigned)f2bf(v1) << 16);
  }
  {
    uint4* dst = (uint4*)&Hl[p * LDW + q * 24];
    dst[0] = make_uint4(pk[0], pk[1], pk[2],  pk[3]);
    dst[1] = make_uint4(pk[4], pk[5], pk[6],  pk[7]);
    dst[2] = make_uint4(pk[8], pk[9], pk[10], pk[11]);
  }
  __syncthreads();                            // Hl + Wl ready

  // ---- MFMA: 4 waves x 16 rows; N=192 (12 tiles), K=96 (3 steps) ----
  int wv = t >> 6, lane = t & 63, r = lane & 15, g = lane >> 4;
  f32x4 acc[12];
  #pragma unroll
  for (int i = 0; i < 12; i++) acc[i] = (f32x4){0.f, 0.f, 0.f, 0.f};
  int arow = (wv * 16 + r) * LDW;
  #pragma unroll
  for (int ks = 0; ks < 3; ks++) {
    v8s a = *(const v8s*)&Hl[arow + ks * 32 + g * 8];
    #pragma unroll
    for (int t16 = 0; t16 < 12; t16++) {
      v8s b = *(const v8s*)&Wl[(t16 * 16 + r) * LDW + ks * 32 + g * 8];
      acc[t16] = __builtin_amdgcn_mfma_f32_16x16x32_bf16(a, b, acc[t16], 0, 0, 0);
    }
  }
  __syncthreads();                            // Wl reads done -> reuse as record stage

  unsigned short* Ol = Wl;                    // [64][REC_S]
  #pragma unroll
  for (int t16 = 0; t16 < 12; t16++) {
    #pragma unroll
    for (int rr = 0; rr < 4; rr++) {
      Ol[(wv * 16 + g * 4 + rr) * REC_S + t16 * 16 + r] = f2bf(acc[t16][rr]);
    }
  }
  if (q == 0) {                               // scalar payload into record tail
    float* tl = (float*)&Ol[p * REC_S + 192];
    tl[0] = sx; tl[1] = sy; tl[2] = sz; tl[3] = sc;
    ((int*)tl)[4] = sb; ((int*)tl)[5] = srk; ((int*)tl)[6] = sbase; ((int*)tl)[7] = scn;
    spos[p] = sps;
  }
  __syncthreads();

  // ---- coalesced record store: 4 threads per point, 112B each ----
  int row = t >> 2, c4 = t & 3;
  long long gp2 = (long long)blockIdx.x * 64 + row;
  if (gp2 < n) {
    const uint4* src = (const uint4*)&Ol[row * REC_S + c4 * 56];
    uint4* dst = (uint4*)(rec + (size_t)spos[row] * REC_B + c4 * 112);
    #pragma unroll
    for (int i = 0; i < 7; i++) dst[i] = src[i];
  }
}

// ---------------- segment max + scalar finalize (window-ownership, no atomics) ----------------
__global__ __launch_bounds__(256) void k_gather(
    const char* __restrict__ rec, float* __restrict__ out, long long n) {
  __shared__ int s_start[256], s_cnt[256], s_rank[256];
  __shared__ int hscan[256];
  int t = threadIdx.x;
  int p0 = blockIdx.x * 64;
  const int* t0 = (const int*)(rec + (size_t)p0 * REC_B + 384);
  int base0 = t0[6], cnt0 = t0[7];
  int range_start = (base0 == p0) ? p0 : base0 + cnt0;
  int p1 = p0 + 64, range_end;
  if (p1 >= (int)n) {
    range_end = (int)n;
  } else {
    const int* t1 = (const int*)(rec + (size_t)p1 * REC_B + 384);
    int base1 = t1[6], cnt1 = t1[7];
    range_end = (base1 == p1) ? p1 : base1 + cnt1;
  }
  int RL = range_end - range_start;           // <= 64 + max_seg  (<< 256)
  int hd = 0, cn_ = 0, rk_ = 0;
  int pp = range_start + t;
  if (t < RL) {
    const int* tf = (const int*)(rec + (size_t)pp * REC_B + 384);
    hd = (tf[6] == pp);
    if (hd) { cn_ = tf[7]; rk_ = tf[5]; }
  }
  hscan[t] = hd;
  __syncthreads();
  for (int o = 1; o < 256; o <<= 1) {
    int x = (t >= o) ? hscan[t - o] : 0;
    __syncthreads();
    hscan[t] += x;
    __syncthreads();
  }
  int ns = hscan[255];
  if (hd) {
    int idx = hscan[t] - 1;
    s_start[idx] = pp; s_cnt[idx] = cn_; s_rank[idx] = rk_;
  }
  __syncthreads();

  int wv = t >> 6, lane = t & 63;
  float* ocrd = out + n * 192;
  float* oxyz = out + n * 196;
  float* ocnt = out + n * 199;
  float* obat = out + n * 200;
  float* oval = out + n * 201;
  for (int j = wv; j < ns; j += 4) {
    int st = s_start[j], cn = s_cnt[j], rk = s_rank[j];
    float ni = __int_as_float(0xff800000);
    float m0 = ni, m1 = ni, m2 = ni;
    for (int qq = 0; qq < cn; qq++) {
      const unsigned short* h = (const unsigned short*)(rec + (size_t)(st + qq) * REC_B);
      m0 = fmaxf(m0, bf2f(h[lane]));
      m1 = fmaxf(m1, bf2f(h[lane + 64]));
      m2 = fmaxf(m2, bf2f(h[lane + 128]));
    }
    float ax = 0.f, ay = 0.f, az = 0.f, ac = 0.f; int ab = 0;
    for (int qq = lane; qq < cn; qq += 64) {
      const float* tf = (const float*)(rec + (size_t)(st + qq) * REC_B + 384);
      float c = tf[3];
      ax += tf[0] * c; ay += tf[1] * c; az += tf[2] * c; ac += c;
      ab += ((const int*)tf)[4];
    }
    for (int o = 32; o; o >>= 1) {
      ax += __shfl_down(ax, o); ay += __shfl_down(ay, o);
      az += __shfl_down(az, o); ac += __shfl_down(ac, o);
      ab += __shfl_down(ab, o);
    }
    float* orow = out + (size_t)rk * COUT;
    orow[lane] = m0; orow[lane + 64] = m1; orow[lane + 128] = m2;
    if (lane == 0) {
      float cs = fmaxf(ac, 1.0f);
      float x = ax / cs, y = ay / cs, z = az / cs;
      int bn = ab / max(cn, 1);
      oxyz[rk*3+0] = x; oxyz[rk*3+1] = y; oxyz[rk*3+2] = z;
      ocnt[rk] = cs;
      obat[rk] = (float)bn;
      oval[rk] = 1.0f;
      ocrd[rk*4+0] = (float)bn;
      ocrd[rk*4+1] = (float)(int)floorf(x * 0.5f);
      ocrd[rk*4+2] = (float)(int)floorf(y * 0.5f);
      ocrd[rk*4+3] = (float)(int)floorf(z * 0.5f);
    }
  }
}

// ---------------- tail rows >= num_unique: zeros + defaults ----------------
__global__ void k_tail(float* __restrict__ out, const int* __restrict__ hdr, long long n) {
  int nu = hdr[0];
  long long s = (long long)blockIdx.x * 4 + (threadIdx.x >> 6);
  if (s < nu || s >= n) return;
  int lane = threadIdx.x & 63;
  float* orow = out + s * COUT;
  orow[lane] = 0.f; orow[lane + 64] = 0.f; orow[lane + 128] = 0.f;
  if (lane == 0) {
    float* ocrd = out + n * 192;
    float* oxyz = out + n * 196;
    float* ocnt = out + n * 199;
    float* obat = out + n * 200;
    float* oval = out + n * 201;
    oxyz[s*3+0] = 0.f; oxyz[s*3+1] = 0.f; oxyz[s*3+2] = 0.f;
    ocnt[s] = 1.0f;
    obat[s] = 0.f;
    oval[s] = 0.f;
    ocrd[s*4+0] = 0.f; ocrd[s*4+1] = 0.f; ocrd[s*4+2] = 0.f; ocrd[s*4+3] = 0.f;
  }
}

extern "C" void kernel_launch(void* const* d_in, const int* in_sizes, int n_in,
                              void* d_out, int out_size, void* d_ws, size_t ws_size,
                              hipStream_t stream) {
  const float* feat  = (const float*)d_in[0];
  const float* xyz   = (const float*)d_in[1];
  const float* xyzc  = (const float*)d_in[2];
  const int*   batch = (const int*)d_in[3];
  const float* W     = (const float*)d_in[4];
  const float* gamma = (const float*)d_in[5];
  const float* beta  = (const float*)d_in[6];
  long long n = in_sizes[3];
  float* out = (float*)d_out;

  // ---- workspace layout (~190 MB) ----
  char* wsb = (char*)d_ws;
  size_t off = 0;
  int* hdr   = (int*)wsb;              off += 256;                // hdr[0] = num_unique
  int* keys  = (int*)(wsb + off);      off += (size_t)n * 4;
  int* slot  = (int*)(wsb + off);      off += (size_t)n * 4;
  off = (off + 255) & ~(size_t)255;
  int* cntk  = (int*)(wsb + off);      off += (size_t)NSC * 4;    // zeroed by k_zero
  int* rankK = (int*)(wsb + off);      off += (size_t)NSC * 4;
  int* posK  = (int*)(wsb + off);      off += (size_t)NSC * 4;
  unsigned long long* bsums = (unsigned long long*)(wsb + off); off += 512 * 8;
  unsigned long long* boffs = (unsigned long long*)(wsb + off); off += 512 * 8;
  off = (off + 255) & ~(size_t)255;
  char* rec  = wsb + off;              off += (size_t)n * REC_B;

  int nb  = (int)((n + 255) / 256);
  int nb64 = (int)((n + 63) / 64);
  k_zero  <<<256, 256, 0, stream>>>((int4*)cntk, NSC / 4);
  k_key   <<<nb, 256, 0, stream>>>(xyz, batch, keys, slot, cntk, (int)n);
  k_scan1 <<<NSC / 1024, 256, 0, stream>>>((const int4*)cntk, bsums);
  k_scan2 <<<1, 256, 0, stream>>>(bsums, boffs, hdr);
  k_scan3 <<<NSC / 1024, 256, 0, stream>>>((const int4*)cntk, boffs, rankK, posK);
  k_H     <<<nb64, 256, 0, stream>>>(feat, xyz, xyzc, batch, W, gamma, beta,
                                     keys, slot, cntk, rankK, posK, rec, n);
  k_gather<<<nb64, 256, 0, stream>>>(rec, out, n);
  k_tail  <<<(int)((n + 3) / 4), 256, 0, stream>>>(out, hdr, n);
}

// Round 6
// 316.724 us; speedup vs baseline: 7.8451x; 1.0790x over previous
//
#include <hip/hip_runtime.h>
#include <math.h>

constexpr int CIN   = 96;
constexpr int COUT  = 192;
constexpr int NSC   = 1 << 19;   // scan span >= 8*40*40*40 = 512000 keys
constexpr int LDW   = 104;       // Hl/Wl row stride (shorts)
constexpr int OST   = 208;       // Ol staging row stride (shorts, 416B = 26*16)
constexpr int TAILB = 64;        // tail record stride (bytes); 48 used

typedef short v8s  __attribute__((ext_vector_type(8)));
typedef float f32x4 __attribute__((ext_vector_type(4)));

__device__ __forceinline__ unsigned short f2bf(float f) {
  unsigned u = __float_as_uint(f);
  u += 0x7fff + ((u >> 16) & 1);          // RNE
  return (unsigned short)(u >> 16);
}
__device__ __forceinline__ float bf2f(unsigned short s) {
  return __uint_as_float((unsigned)s << 16);
}
// fields: [62:42]=presence (rank), [41:21]=multi count (mpos), [20:0]=count (pos)
__device__ __forceinline__ unsigned long long pack3(int c) {
  return ((unsigned long long)(c > 0) << 42)
       | ((unsigned long long)((c >= 2) ? c : 0) << 21)
       | (unsigned long long)(unsigned)c;
}

// ---------------- fast zero ----------------
__global__ void k_zero(int4* __restrict__ p, int n4) {
  int i = blockIdx.x * blockDim.x + threadIdx.x;
  int s = gridDim.x * blockDim.x;
  int4 z = make_int4(0, 0, 0, 0);
  for (; i < n4; i += s) p[i] = z;
}

// ---------------- keys + per-point slot + per-key counts ----------------
__global__ void k_key(const float* __restrict__ xyz, const int* __restrict__ batch,
                      int* __restrict__ keys, int* __restrict__ slot,
                      int* __restrict__ cntk, int n) {
  int i = blockIdx.x * blockDim.x + threadIdx.x;
  if (i >= n) return;
  int vx = min(max((int)floorf(xyz[3*i+0] * 0.5f), 0), 39);
  int vy = min(max((int)floorf(xyz[3*i+1] * 0.5f), 0), 39);
  int vz = min(max((int)floorf(xyz[3*i+2] * 0.5f), 0), 39);
  int key = ((batch[i] * 40 + vx) * 40 + vy) * 40 + vz;   // lexicographic, < 512000
  keys[i] = key;
  slot[i] = atomicAdd(&cntk[key], 1);
}

// ---------------- triple prefix scan ----------------
__global__ void k_scan1(const int4* __restrict__ cnt4,
                        unsigned long long* __restrict__ bsums) {
  int t = threadIdx.x;
  int4 v = cnt4[(size_t)blockIdx.x * 256 + t];
  unsigned long long s = pack3(v.x) + pack3(v.y) + pack3(v.z) + pack3(v.w);
  for (int o = 32; o; o >>= 1) s += __shfl_down(s, o);
  __shared__ unsigned long long wsum[4];
  if ((t & 63) == 0) wsum[t >> 6] = s;
  __syncthreads();
  if (t == 0) bsums[blockIdx.x] = wsum[0] + wsum[1] + wsum[2] + wsum[3];
}

__global__ void k_scan2(const unsigned long long* __restrict__ bsums,
                        unsigned long long* __restrict__ boffs,
                        int* __restrict__ hdr) {
  __shared__ unsigned long long tmp[256];
  int t = threadIdx.x;                      // 256 threads, 512 sums
  unsigned long long v0 = bsums[2*t], v1 = bsums[2*t+1];
  unsigned long long s = v0 + v1;
  tmp[t] = s;
  __syncthreads();
  for (int o = 1; o < 256; o <<= 1) {
    unsigned long long x = (t >= o) ? tmp[t - o] : 0ULL;
    __syncthreads();
    tmp[t] += x;
    __syncthreads();
  }
  unsigned long long base = tmp[t] - s;
  boffs[2*t] = base;
  boffs[2*t+1] = base + v0;
  if (t == 255) hdr[0] = (int)(tmp[255] >> 42);   // num_unique
}

__global__ void k_scan3(const int4* __restrict__ cnt4,
                        const unsigned long long* __restrict__ boffs,
                        int* __restrict__ rankK, int* __restrict__ posK,
                        int* __restrict__ mposK) {
  int t = threadIdx.x, b = blockIdx.x;
  int4 v = cnt4[(size_t)b * 256 + t];
  unsigned long long q0 = pack3(v.x), q1 = pack3(v.y), q2 = pack3(v.z), q3 = pack3(v.w);
  unsigned long long s = q0 + q1 + q2 + q3;
  __shared__ unsigned long long tmp[256];
  tmp[t] = s;
  __syncthreads();
  for (int o = 1; o < 256; o <<= 1) {
    unsigned long long x = (t >= o) ? tmp[t - o] : 0ULL;
    __syncthreads();
    tmp[t] += x;
    __syncthreads();
  }
  unsigned long long e0 = boffs[b] + tmp[t] - s;
  unsigned long long e1 = e0 + q0, e2 = e1 + q1, e3 = e2 + q2;
  const unsigned M = 0x1FFFFF;
  int4 rk = make_int4((int)(e0 >> 42), (int)(e1 >> 42), (int)(e2 >> 42), (int)(e3 >> 42));
  int4 mp = make_int4((int)((e0 >> 21) & M), (int)((e1 >> 21) & M),
                      (int)((e2 >> 21) & M), (int)((e3 >> 21) & M));
  int4 ps = make_int4((int)(e0 & M), (int)(e1 & M), (int)(e2 & M), (int)(e3 & M));
  ((int4*)rankK)[(size_t)b * 256 + t] = rk;
  ((int4*)posK )[(size_t)b * 256 + t] = ps;
  ((int4*)mposK)[(size_t)b * 256 + t] = mp;
}

// ---------------- LayerNorm + MFMA Linear -> direct out / overflow + tail ----------------
__global__ __launch_bounds__(256) void k_H(
    const float* __restrict__ feat, const float* __restrict__ xyz,
    const float* __restrict__ xyzc, const int* __restrict__ batch,
    const float* __restrict__ W, const float* __restrict__ gamma,
    const float* __restrict__ beta, const int* __restrict__ keys,
    const int* __restrict__ slot, const int* __restrict__ cntk,
    const int* __restrict__ rankK, const int* __restrict__ posK,
    const int* __restrict__ mposK, float* __restrict__ out,
    unsigned short* __restrict__ ov, char* __restrict__ tail, long long n) {
  __shared__ unsigned short Wl[COUT * LDW];   // 39936B; reused as Ol[64][OST]
  __shared__ unsigned short Hl[64 * LDW];     // 13312B
  __shared__ float g_lds[CIN], b_lds[CIN];
  __shared__ int Tl[64][16];                  // scalar payload per point (64B recs)
  int t = threadIdx.x;
  if (t < CIN) { g_lds[t] = gamma[t]; b_lds[t] = beta[t]; }

  // ---- stage W (fp32 -> bf16) ----
  #pragma unroll
  for (int i = 0; i < 18; i++) {
    int f4 = t + 256 * i;                    // 4608 float4 total
    float4 w = ((const float4*)W)[f4];
    int flat = f4 * 4;
    int row = flat / CIN, col = flat % CIN;
    uint2 pk2;
    pk2.x = (unsigned)f2bf(w.x) | ((unsigned)f2bf(w.y) << 16);
    pk2.y = (unsigned)f2bf(w.z) | ((unsigned)f2bf(w.w) << 16);
    *(uint2*)&Wl[row * LDW + col] = pk2;
  }

  // ---- LayerNorm: 4 threads per point ----
  int p = t >> 2, q = t & 3;
  long long gp = (long long)blockIdx.x * 64 + p;
  if (q == 0 && gp < n) {                    // per-point scalar payload -> Tl
    int key = keys[gp];
    int sl  = slot[gp];
    Tl[p][0] = __float_as_int(xyz[gp*3+0]);
    Tl[p][1] = __float_as_int(xyz[gp*3+1]);
    Tl[p][2] = __float_as_int(xyz[gp*3+2]);
    Tl[p][3] = __float_as_int(xyzc[gp]);
    Tl[p][4] = batch[gp];
    Tl[p][5] = rankK[key];
    Tl[p][6] = posK[key];                    // segment base in point stream
    Tl[p][7] = cntk[key];
    Tl[p][8] = mposK[key];                   // segment base in overflow stream
    Tl[p][9] = sl;
    Tl[p][10] = 0; Tl[p][11] = 0;
  }
  float fv[24];
  float sum = 0.f, sq = 0.f;
  if (gp < n) {
    const float* fr = feat + gp * CIN + q * 24;
    #pragma unroll
    for (int j = 0; j < 24; j += 4) {
      float4 x = *(const float4*)(fr + j);
      fv[j] = x.x; fv[j+1] = x.y; fv[j+2] = x.z; fv[j+3] = x.w;
    }
    #pragma unroll
    for (int j = 0; j < 24; j++) { sum += fv[j]; sq += fv[j] * fv[j]; }
  } else {
    #pragma unroll
    for (int j = 0; j < 24; j++) fv[j] = 0.f;
  }
  sum += __shfl_xor(sum, 1); sq += __shfl_xor(sq, 1);
  sum += __shfl_xor(sum, 2); sq += __shfl_xor(sq, 2);
  float mu   = sum * (1.f / CIN);
  float var  = sq  * (1.f / CIN) - mu * mu;
  float rstd = rsqrtf(var + 1e-6f);
  __syncthreads();                            // g_lds/b_lds + Wl visible
  unsigned pk[12];
  #pragma unroll
  for (int j = 0; j < 12; j++) {
    int k = q * 24 + 2 * j;
    float v0 = (fv[2*j]   - mu) * rstd * g_lds[k]   + b_lds[k];
    float v1 = (fv[2*j+1] - mu) * rstd * g_lds[k+1] + b_lds[k+1];
    pk[j] = (unsigned)f2bf(v0) | ((unsigned)f2bf(v1) << 16);
  }
  {
    uint4* dst = (uint4*)&Hl[p * LDW + q * 24];
    dst[0] = make_uint4(pk[0], pk[1], pk[2],  pk[3]);
    dst[1] = make_uint4(pk[4], pk[5], pk[6],  pk[7]);
    dst[2] = make_uint4(pk[8], pk[9], pk[10], pk[11]);
  }
  __syncthreads();                            // Hl + Wl ready

  // ---- MFMA: 4 waves x 16 rows; N=192 (12 tiles), K=96 (3 steps) ----
  int wv = t >> 6, lane = t & 63, r = lane & 15, g = lane >> 4;
  f32x4 acc[12];
  #pragma unroll
  for (int i = 0; i < 12; i++) acc[i] = (f32x4){0.f, 0.f, 0.f, 0.f};
  int arow = (wv * 16 + r) * LDW;
  #pragma unroll
  for (int ks = 0; ks < 3; ks++) {
    v8s a = *(const v8s*)&Hl[arow + ks * 32 + g * 8];
    #pragma unroll
    for (int t16 = 0; t16 < 12; t16++) {
      v8s b = *(const v8s*)&Wl[(t16 * 16 + r) * LDW + ks * 32 + g * 8];
      acc[t16] = __builtin_amdgcn_mfma_f32_16x16x32_bf16(a, b, acc[t16], 0, 0, 0);
    }
  }
  __syncthreads();                            // Wl reads done -> reuse as Ol

  unsigned short* Ol = Wl;                    // [64][OST]
  #pragma unroll
  for (int t16 = 0; t16 < 12; t16++) {
    #pragma unroll
    for (int rr = 0; rr < 4; rr++) {
      Ol[(wv * 16 + g * 4 + rr) * OST + t16 * 16 + r] = f2bf(acc[t16][rr]);
    }
  }
  __syncthreads();

  // ---- store: 4 threads per point ----
  int row = t >> 2, c4 = t & 3;
  long long gp2 = (long long)blockIdx.x * 64 + row;
  if (gp2 < n) {
    int rk = Tl[row][5], cn = Tl[row][7], mb = Tl[row][8], sl = Tl[row][9];
    const unsigned short* src = &Ol[row * OST + c4 * 48];
    if (cn == 1) {                            // final output row, f32
      float* dst = out + (size_t)rk * COUT + c4 * 48;
      #pragma unroll
      for (int i = 0; i < 12; i++) {
        uint2 s2 = *(const uint2*)&src[i * 4];
        float4 f;
        f.x = bf2f((unsigned short)(s2.x & 0xffff));
        f.y = bf2f((unsigned short)(s2.x >> 16));
        f.z = bf2f((unsigned short)(s2.y & 0xffff));
        f.w = bf2f((unsigned short)(s2.y >> 16));
        *(float4*)&dst[i * 4] = f;
      }
    } else {                                  // overflow row, bf16
      unsigned short* dst = ov + (size_t)(mb + sl) * COUT + c4 * 48;
      #pragma unroll
      for (int i = 0; i < 6; i++)
        ((uint4*)dst)[i] = ((const uint4*)src)[i];
    }
    if (c4 == 0) {                            // 48B tail record at point-stream pos
      int pos = Tl[row][6] + sl;
      uint4* td = (uint4*)(tail + (size_t)pos * TAILB);
      const uint4* ts = (const uint4*)&Tl[row][0];
      td[0] = ts[0]; td[1] = ts[1]; td[2] = ts[2];
    }
  }
}

// ---------------- segment reduce (gather role) + tail defaults (tail role) ----------------
__global__ __launch_bounds__(256) void k_gat(
    const char* __restrict__ tail, const unsigned short* __restrict__ ov,
    const int* __restrict__ hdr, float* __restrict__ out, long long n, int nb64) {
  int t = threadIdx.x;
  int lane = t & 63, wv = t >> 6;
  float* ocrd = out + n * 192;
  float* oxyz = out + n * 196;
  float* ocnt = out + n * 199;
  float* obat = out + n * 200;
  float* oval = out + n * 201;

  if ((int)blockIdx.x >= nb64) {              // ---- tail role ----
    int nu = hdr[0];
    long long s = (long long)(blockIdx.x - nb64) * 4 + wv;
    if (s < nu || s >= n) return;
    float* orow = out + s * COUT;
    orow[lane] = 0.f; orow[lane + 64] = 0.f; orow[lane + 128] = 0.f;
    if (lane == 0) {
      oxyz[s*3+0] = 0.f; oxyz[s*3+1] = 0.f; oxyz[s*3+2] = 0.f;
      ocnt[s] = 1.0f;  obat[s] = 0.f;  oval[s] = 0.f;
      ocrd[s*4+0] = 0.f; ocrd[s*4+1] = 0.f; ocrd[s*4+2] = 0.f; ocrd[s*4+3] = 0.f;
    }
    return;
  }

  // ---- gather role: window of 64 point-stream records ----
  __shared__ int s_start[256], s_cnt[256], s_rank[256], s_mb[256];
  __shared__ int hscan[256];
  int p0 = blockIdx.x * 64;
  const int* t0 = (const int*)(tail + (size_t)p0 * TAILB);
  int base0 = t0[6], cnt0 = t0[7];
  int range_start = (base0 == p0) ? p0 : base0 + cnt0;
  int p1 = p0 + 64, range_end;
  if (p1 >= (int)n) {
    range_end = (int)n;
  } else {
    const int* t1 = (const int*)(tail + (size_t)p1 * TAILB);
    int base1 = t1[6], cnt1 = t1[7];
    range_end = (base1 == p1) ? p1 : base1 + cnt1;
  }
  int RL = range_end - range_start;
  int hd = 0, cn_ = 0, rk_ = 0, mb_ = 0;
  int pp = range_start + t;
  if (t < RL) {
    const int* tf = (const int*)(tail + (size_t)pp * TAILB);
    hd = (tf[6] == pp);
    if (hd) { cn_ = tf[7]; rk_ = tf[5]; mb_ = tf[8]; }
  }
  hscan[t] = hd;
  __syncthreads();
  for (int o = 1; o < 256; o <<= 1) {
    int x = (t >= o) ? hscan[t - o] : 0;
    __syncthreads();
    hscan[t] += x;
    __syncthreads();
  }
  int ns = hscan[255];
  if (hd) {
    int idx = hscan[t] - 1;
    s_start[idx] = pp; s_cnt[idx] = cn_; s_rank[idx] = rk_; s_mb[idx] = mb_;
  }
  __syncthreads();

  for (int j = wv; j < ns; j += 4) {
    int st = s_start[j], cn = s_cnt[j], rk = s_rank[j], mb = s_mb[j];
    // scalar sums over the segment's tail records
    float ax = 0.f, ay = 0.f, az = 0.f, ac = 0.f; int ab = 0;
    for (int qq = lane; qq < cn; qq += 64) {
      const float* tf = (const float*)(tail + (size_t)(st + qq) * TAILB);
      float c = tf[3];
      ax += tf[0] * c; ay += tf[1] * c; az += tf[2] * c; ac += c;
      ab += ((const int*)tf)[4];
    }
    for (int o = 32; o; o >>= 1) {
      ax += __shfl_down(ax, o); ay += __shfl_down(ay, o);
      az += __shfl_down(az, o); ac += __shfl_down(ac, o);
      ab += __shfl_down(ab, o);
    }
    if (cn > 1) {                             // feat max from overflow stream
      float ni = __int_as_float(0xff800000);
      float m0 = ni, m1 = ni, m2 = ni;
      for (int qq = 0; qq < cn; qq++) {
        const unsigned short* h = ov + (size_t)(mb + qq) * COUT;
        m0 = fmaxf(m0, bf2f(h[lane]));
        m1 = fmaxf(m1, bf2f(h[lane + 64]));
        m2 = fmaxf(m2, bf2f(h[lane + 128]));
      }
      float* orow = out + (size_t)rk * COUT;
      orow[lane] = m0; orow[lane + 64] = m1; orow[lane + 128] = m2;
    }
    if (lane == 0) {
      float cs = fmaxf(ac, 1.0f);
      float x = ax / cs, y = ay / cs, z = az / cs;
      int bn = ab / max(cn, 1);
      oxyz[rk*3+0] = x; oxyz[rk*3+1] = y; oxyz[rk*3+2] = z;
      ocnt[rk] = cs;
      obat[rk] = (float)bn;
      oval[rk] = 1.0f;
      ocrd[rk*4+0] = (float)bn;
      ocrd[rk*4+1] = (float)(int)floorf(x * 0.5f);
      ocrd[rk*4+2] = (float)(int)floorf(y * 0.5f);
      ocrd[rk*4+3] = (float)(int)floorf(z * 0.5f);
    }
  }
}

extern "C" void kernel_launch(void* const* d_in, const int* in_sizes, int n_in,
                              void* d_out, int out_size, void* d_ws, size_t ws_size,
                              hipStream_t stream) {
  const float* feat  = (const float*)d_in[0];
  const float* xyz   = (const float*)d_in[1];
  const float* xyzc  = (const float*)d_in[2];
  const int*   batch = (const int*)d_in[3];
  const float* W     = (const float*)d_in[4];
  const float* gamma = (const float*)d_in[5];
  const float* beta  = (const float*)d_in[6];
  long long n = in_sizes[3];
  float* out = (float*)d_out;

  // ---- workspace layout (~215 MB) ----
  char* wsb = (char*)d_ws;
  size_t off = 0;
  int* hdr   = (int*)wsb;              off += 256;                // hdr[0] = num_unique
  int* keys  = (int*)(wsb + off);      off += (size_t)n * 4;
  int* slot  = (int*)(wsb + off);      off += (size_t)n * 4;
  off = (off + 255) & ~(size_t)255;
  int* cntk  = (int*)(wsb + off);      off += (size_t)NSC * 4;    // zeroed by k_zero
  int* rankK = (int*)(wsb + off);      off += (size_t)NSC * 4;
  int* posK  = (int*)(wsb + off);      off += (size_t)NSC * 4;
  int* mposK = (int*)(wsb + off);      off += (size_t)NSC * 4;
  unsigned long long* bsums = (unsigned long long*)(wsb + off); off += 512 * 8;
  unsigned long long* boffs = (unsigned long long*)(wsb + off); off += 512 * 8;
  off = (off + 255) & ~(size_t)255;
  char* tail = wsb + off;              off += (size_t)n * TAILB;
  off = (off + 255) & ~(size_t)255;
  unsigned short* ovf = (unsigned short*)(wsb + off);  off += (size_t)n * COUT * 2;

  int nb   = (int)((n + 255) / 256);
  int nb64 = (int)((n + 63) / 64);
  int ntail = (int)((n + 3) / 4);
  k_zero  <<<256, 256, 0, stream>>>((int4*)cntk, NSC / 4);
  k_key   <<<nb, 256, 0, stream>>>(xyz, batch, keys, slot, cntk, (int)n);
  k_scan1 <<<NSC / 1024, 256, 0, stream>>>((const int4*)cntk, bsums);
  k_scan2 <<<1, 256, 0, stream>>>(bsums, boffs, hdr);
  k_scan3 <<<NSC / 1024, 256, 0, stream>>>((const int4*)cntk, boffs, rankK, posK, mposK);
  k_H     <<<nb64, 256, 0, stream>>>(feat, xyz, xyzc, batch, W, gamma, beta,
                                     keys, slot, cntk, rankK, posK, mposK,
                                     out, ovf, tail, n);
  k_gat   <<<nb64 + ntail, 256, 0, stream>>>(tail, ovf, hdr, out, n, nb64);
}